// Round 2
// baseline (2299.789 us; speedup 1.0000x reference)
//
#include <hip/hip_runtime.h>
#include <hip/hip_bf16.h>
#include <cmath>

#define BB 2
#define LL 2048
#define DMODEL 1024
#define DIN 2048
#define NST 16

// ---------------------------------------------------------------------------
// Tiled f32 GEMM, C[m,n] = sum_k A[m*lda+k] * B[n*ldb+k]   ("NT": both K-major)
// 64x64 tile, BK=16, 256 threads, 4x4 per thread.
// SOFTPLUS_BIAS: C = softplus(acc + bias[n])
// ---------------------------------------------------------------------------
template <bool SOFTPLUS_BIAS>
__global__ __launch_bounds__(256) void gemm_nt(const float* __restrict__ A, int lda,
                                               const float* __restrict__ B, int ldb,
                                               float* __restrict__ C, int ldc,
                                               int K, const float* __restrict__ bias) {
    const int bm = blockIdx.y * 64;
    const int bn = blockIdx.x * 64;
    __shared__ __align__(16) float As[16][68];
    __shared__ __align__(16) float Bs[16][68];
    const int tid = threadIdx.x;
    const int tx = tid & 15;   // n-sub tile
    const int ty = tid >> 4;   // m-sub tile
    float acc[4][4] = {};

    for (int k0 = 0; k0 < K; k0 += 16) {
#pragma unroll
        for (int i = 0; i < 4; ++i) {
            int idx = tid + i * 256;
            int r = idx >> 4;   // 0..63
            int c = idx & 15;   // 0..15
            As[c][r] = A[(size_t)(bm + r) * lda + k0 + c];
            Bs[c][r] = B[(size_t)(bn + r) * ldb + k0 + c];
        }
        __syncthreads();
#pragma unroll
        for (int k = 0; k < 16; ++k) {
            float4 a4 = *reinterpret_cast<const float4*>(&As[k][ty * 4]);
            float4 b4 = *reinterpret_cast<const float4*>(&Bs[k][tx * 4]);
            float av[4] = {a4.x, a4.y, a4.z, a4.w};
            float bv[4] = {b4.x, b4.y, b4.z, b4.w};
#pragma unroll
            for (int i = 0; i < 4; ++i)
#pragma unroll
                for (int j = 0; j < 4; ++j)
                    acc[i][j] = fmaf(av[i], bv[j], acc[i][j]);
        }
        __syncthreads();
    }

#pragma unroll
    for (int i = 0; i < 4; ++i) {
        int m = bm + ty * 4 + i;
#pragma unroll
        for (int j = 0; j < 4; ++j) {
            int n = bn + tx * 4 + j;
            float v = acc[i][j];
            if (SOFTPLUS_BIAS) {
                v += bias[n];
                v = (v > 20.0f) ? v : log1pf(__expf(v));
            }
            C[(size_t)m * ldc + n] = v;
        }
    }
}

// ---------------------------------------------------------------------------
// Depthwise causal conv (K=4) + bias + SiLU.
// x_p comes from xz[..., 0:2048] (row stride 4096). Output xs (B,L,DIN) dense.
// ---------------------------------------------------------------------------
__global__ __launch_bounds__(256) void conv_silu(const float* __restrict__ xz,
                                                 const float* __restrict__ w,
                                                 const float* __restrict__ b,
                                                 float* __restrict__ xs) {
    int idx = blockIdx.x * 256 + threadIdx.x;   // over B*L*DIN = 2^23
    int d = idx & (DIN - 1);
    int t = (idx >> 11) & (LL - 1);
    int bb = idx >> 22;
    const float* xp = xz + (size_t)bb * LL * 4096;
    float acc = b[d];
#pragma unroll
    for (int k = 0; k < 4; ++k) {
        int tt = t - 3 + k;
        if (tt >= 0) acc = fmaf(w[d * 4 + k], xp[(size_t)tt * 4096 + d], acc);
    }
    float sig = 1.0f / (1.0f + __expf(-acc));
    xs[idx] = acc * sig;
}

// ---------------------------------------------------------------------------
// B/C projections: Bp[bt,n] = <xs[bt,:], B_proj_w[n,:]>, same for Cp.
// One block per (b,t) row; xs row staged in LDS; 4 waves x 8 outputs each.
// ---------------------------------------------------------------------------
__global__ __launch_bounds__(256) void bc_proj(const float* __restrict__ xs,
                                               const float* __restrict__ Bw,
                                               const float* __restrict__ Cw,
                                               float* __restrict__ Bp,
                                               float* __restrict__ Cp) {
    __shared__ float row[DIN];
    const int bt = blockIdx.x;
    const float* xr = xs + (size_t)bt * DIN;
    for (int i = threadIdx.x; i < DIN; i += 256) row[i] = xr[i];
    __syncthreads();
    const int wave = threadIdx.x >> 6;
    const int lane = threadIdx.x & 63;
    for (int o = wave; o < 32; o += 4) {
        const float* wrow = (o < 16) ? (Bw + (size_t)o * DIN) : (Cw + (size_t)(o - 16) * DIN);
        float s = 0.0f;
        for (int i = lane; i < DIN; i += 64) s = fmaf(row[i], wrow[i], s);
#pragma unroll
        for (int off = 32; off > 0; off >>= 1) s += __shfl_down(s, off);
        if (lane == 0) {
            if (o < 16) Bp[(size_t)bt * 16 + o] = s;
            else        Cp[(size_t)bt * 16 + (o - 16)] = s;
        }
    }
}

// ---------------------------------------------------------------------------
// Selective scan: one thread per (b,d) channel, 16 states in registers.
// Fuses +D*xs and *silu(z). Writes y_gated into xz[..., 0:2048] (stride 4096).
// Distance-1 software prefetch of all per-t operands.
// ---------------------------------------------------------------------------
__global__ __launch_bounds__(64) void scan_kernel(const float* __restrict__ dt,
                                                  const float* __restrict__ xs,
                                                  float* __restrict__ xz,
                                                  const float* __restrict__ Bp,
                                                  const float* __restrict__ Cp,
                                                  const float* __restrict__ A_log,
                                                  const float* __restrict__ Dp) {
    const int gid = blockIdx.x * 64 + threadIdx.x;  // 0..4095
    const int b = gid >> 11;
    const int d = gid & (DIN - 1);

    float Ac[NST];
#pragma unroll
    for (int n = 0; n < NST; ++n) Ac[n] = -__expf(A_log[d * NST + n]);
    const float Dv = Dp[d];

    const float* dtp = dt + (size_t)b * LL * DIN + d;
    const float* xsp = xs + (size_t)b * LL * DIN + d;
    const float* zp  = xz + (size_t)b * LL * 4096 + DIN + d;
    float*       yp  = xz + (size_t)b * LL * 4096 + d;
    const float* Bpb = Bp + (size_t)b * LL * NST;
    const float* Cpb = Cp + (size_t)b * LL * NST;

    float h[NST];
#pragma unroll
    for (int n = 0; n < NST; ++n) h[n] = 0.0f;

    // preload t = 0
    float dtv = dtp[0];
    float xv  = xsp[0];
    float zv  = zp[0];
    float bp[NST], cp[NST];
#pragma unroll
    for (int n = 0; n < NST; ++n) { bp[n] = Bpb[n]; cp[n] = Cpb[n]; }

    for (int t = 0; t < LL; ++t) {
        float dtn = 0.f, xn = 0.f, zn = 0.f;
        float bpn[NST], cpn[NST];
        if (t + 1 < LL) {
            dtn = dtp[(size_t)(t + 1) * DIN];
            xn  = xsp[(size_t)(t + 1) * DIN];
            zn  = zp[(size_t)(t + 1) * 4096];
#pragma unroll
            for (int n = 0; n < NST; ++n) {
                bpn[n] = Bpb[(t + 1) * NST + n];
                cpn[n] = Cpb[(t + 1) * NST + n];
            }
        } else {
#pragma unroll
            for (int n = 0; n < NST; ++n) { bpn[n] = 0.f; cpn[n] = 0.f; }
        }

        const float bx = dtv * xv;
        float y = 0.0f;
#pragma unroll
        for (int n = 0; n < NST; ++n) {
            float a = __expf(dtv * Ac[n]);
            h[n] = fmaf(a, h[n], bx * bp[n]);
            y = fmaf(h[n], cp[n], y);
        }
        y = fmaf(Dv, xv, y);
        float g = zv / (1.0f + __expf(-zv));
        yp[(size_t)t * 4096] = y * g;

        dtv = dtn; xv = xn; zv = zn;
#pragma unroll
        for (int n = 0; n < NST; ++n) { bp[n] = bpn[n]; cp[n] = cpn[n]; }
    }
}

// ---------------------------------------------------------------------------
extern "C" void kernel_launch(void* const* d_in, const int* in_sizes, int n_in,
                              void* d_out, int out_size, void* d_ws, size_t ws_size,
                              hipStream_t stream) {
    const float* x          = (const float*)d_in[0];
    const float* in_proj_w  = (const float*)d_in[1];
    const float* conv_w     = (const float*)d_in[2];
    const float* conv_b     = (const float*)d_in[3];
    const float* dt_w       = (const float*)d_in[4];
    const float* dt_b       = (const float*)d_in[5];
    const float* B_proj_w   = (const float*)d_in[6];
    const float* C_proj_w   = (const float*)d_in[7];
    const float* A_log      = (const float*)d_in[8];
    const float* D_param    = (const float*)d_in[9];
    const float* out_proj_w = (const float*)d_in[10];
    float* out = (float*)d_out;
    float* ws  = (float*)d_ws;

    float* xz  = ws;                    // (B,L,4096) = 16,777,216 floats
    float* xs  = ws + 16777216;         // (B,L,2048) =  8,388,608
    float* dtv = ws + 25165824;         // (B,L,2048) =  8,388,608
    float* Bp  = ws + 33554432;         // (B,L,16)   =     65,536
    float* Cp  = ws + 33619968;         // (B,L,16)   =     65,536

    const int M = BB * LL;  // 4096

    // 1. xz = x @ in_proj_w^T   (M=4096, N=4096, K=1024)
    gemm_nt<false><<<dim3(4096 / 64, M / 64), 256, 0, stream>>>(
        x, DMODEL, in_proj_w, DMODEL, xz, 4096, DMODEL, nullptr);

    // 2. causal depthwise conv + bias + silu -> xs
    conv_silu<<<(BB * LL * DIN) / 256, 256, 0, stream>>>(xz, conv_w, conv_b, xs);

    // 3. dt = softplus(xs @ dt_w^T + dt_b)   (M=4096, N=2048, K=2048)
    gemm_nt<true><<<dim3(DIN / 64, M / 64), 256, 0, stream>>>(
        xs, DIN, dt_w, DIN, dtv, DIN, DIN, dt_b);

    // 3b. Bp, Cp projections
    bc_proj<<<M, 256, 0, stream>>>(xs, B_proj_w, C_proj_w, Bp, Cp);

    // 4. selective scan (+D*xs, *silu(z)); writes y_gated into xz[:, :2048]
    scan_kernel<<<64, 64, 0, stream>>>(dtv, xs, xz, Bp, Cp, A_log, D_param);

    // 5. out = y_gated @ out_proj_w^T   (M=4096, N=1024, K=2048)
    gemm_nt<false><<<dim3(DMODEL / 64, M / 64), 256, 0, stream>>>(
        xz, 4096, out_proj_w, DIN, out, DMODEL, DIN, nullptr);
}

// Round 4
// 567.441 us; speedup vs baseline: 4.0529x; 4.0529x over previous
//
#include <hip/hip_runtime.h>
#include <cmath>

#define BB 2
#define LL 2048
#define DMODEL 1024
#define DIN 2048
#define NST 16
#define NC 32      // scan chunks
#define TC 64      // timesteps per chunk

typedef short short8 __attribute__((ext_vector_type(8)));
typedef float f32x4 __attribute__((ext_vector_type(4)));
typedef unsigned short u16;

__device__ __forceinline__ float bf2f(u16 u) {
    union { unsigned u; float f; } v; v.u = ((unsigned)u) << 16; return v.f;
}
__device__ __forceinline__ u16 f2bf(float f) {
    union { float f; unsigned u; } v; v.f = f;
    unsigned r = v.u + 0x7FFFu + ((v.u >> 16) & 1u);
    return (u16)(r >> 16);
}

// ---------------------------------------------------------------------------
// f32 -> bf16 conversion, 4 elements/thread
// ---------------------------------------------------------------------------
__global__ __launch_bounds__(256) void cvt_bf16(const float* __restrict__ in,
                                                u16* __restrict__ out) {
    int i = (blockIdx.x * 256 + threadIdx.x) * 4;
    float4 v = *reinterpret_cast<const float4*>(in + i);
    ushort4 o = {f2bf(v.x), f2bf(v.y), f2bf(v.z), f2bf(v.w)};
    *reinterpret_cast<ushort4*>(out + i) = o;
}

// ---------------------------------------------------------------------------
// bf16 MFMA GEMM (m97 structure): C[m,n] = sum_k A[m,k]*B[n,k], f32 out.
// 128x128 tile, BK=32, 256 thr (4 waves 2x2), 16x16x32 MFMA, 4x4 frags/wave.
// global_load_lds width=16, linear LDS [128][32]. EPI=1: softplus(acc+bias[n]).
// ---------------------------------------------------------------------------
template <int EPI>
__global__ __launch_bounds__(256) void gemm_mfma(const u16* __restrict__ A,
                                                 const u16* __restrict__ B,
                                                 float* __restrict__ C,
                                                 int N, int K,
                                                 const float* __restrict__ bias) {
    __shared__ u16 As[128 * 32];
    __shared__ u16 Bs[128 * 32];
    const int tid = threadIdx.x;
    const int lane = tid & 63;
    const int wave = tid >> 6;
    const int bm = blockIdx.y * 128;
    const int bn = blockIdx.x * 128;
    const int wr = (wave >> 1) * 64;
    const int wc = (wave & 1) * 64;

    f32x4 acc[4][4];
#pragma unroll
    for (int i = 0; i < 4; ++i)
#pragma unroll
        for (int j = 0; j < 4; ++j) acc[i][j] = (f32x4){0.f, 0.f, 0.f, 0.f};

    const int frow = lane & 15;        // fragment row/col within 16
    const int kch = (lane >> 4) * 8;   // k-chunk offset (8 bf16)

    for (int k0 = 0; k0 < K; k0 += 32) {
#pragma unroll
        for (int i = 0; i < 2; ++i) {
            int slot = i * 256 + tid;          // 0..511, 16B each
            int r = slot >> 2;                 // tile row 0..127
            int c8 = (slot & 3) * 8;           // 8-elem column chunk
            __builtin_amdgcn_global_load_lds(
                (const __attribute__((address_space(1))) void*)(A + (size_t)(bm + r) * K + k0 + c8),
                (__attribute__((address_space(3))) void*)(As + slot * 8), 16, 0, 0);
            __builtin_amdgcn_global_load_lds(
                (const __attribute__((address_space(1))) void*)(B + (size_t)(bn + r) * K + k0 + c8),
                (__attribute__((address_space(3))) void*)(Bs + slot * 8), 16, 0, 0);
        }
        __syncthreads();   // compiler drains vmcnt(0) before barrier

        short8 af[4], bf[4];
#pragma unroll
        for (int mi = 0; mi < 4; ++mi)
            af[mi] = *reinterpret_cast<const short8*>(As + (wr + mi * 16 + frow) * 32 + kch);
#pragma unroll
        for (int ni = 0; ni < 4; ++ni)
            bf[ni] = *reinterpret_cast<const short8*>(Bs + (wc + ni * 16 + frow) * 32 + kch);
#pragma unroll
        for (int mi = 0; mi < 4; ++mi)
#pragma unroll
            for (int ni = 0; ni < 4; ++ni)
                acc[mi][ni] = __builtin_amdgcn_mfma_f32_16x16x32_bf16(
                    af[mi], bf[ni], acc[mi][ni], 0, 0, 0);
        __syncthreads();   // protect LDS before next-stage overwrite
    }

    const int crow0 = (lane >> 4) * 4;
    const int ccol = lane & 15;
#pragma unroll
    for (int mi = 0; mi < 4; ++mi) {
#pragma unroll
        for (int ni = 0; ni < 4; ++ni) {
            const int col = bn + wc + ni * 16 + ccol;
            float bv = (EPI == 1) ? bias[col] : 0.f;
#pragma unroll
            for (int r = 0; r < 4; ++r) {
                const int row = bm + wr + mi * 16 + crow0 + r;
                float v = acc[mi][ni][r];
                if (EPI == 1) {
                    v += bv;
                    v = (v > 20.0f) ? v : log1pf(__expf(v));
                }
                C[(size_t)row * N + col] = v;
            }
        }
    }
}

// ---------------------------------------------------------------------------
// Depthwise causal conv (K=4) + bias + SiLU -> xs (bf16)
// ---------------------------------------------------------------------------
__global__ __launch_bounds__(256) void conv_silu(const float* __restrict__ xz,
                                                 const float* __restrict__ w,
                                                 const float* __restrict__ b,
                                                 u16* __restrict__ xsb) {
    int idx = blockIdx.x * 256 + threadIdx.x;   // B*L*DIN
    int d = idx & (DIN - 1);
    int t = (idx >> 11) & (LL - 1);
    int bb = idx >> 22;
    const float* xp = xz + (size_t)bb * LL * 4096;
    float acc = b[d];
#pragma unroll
    for (int k = 0; k < 4; ++k) {
        int tt = t - 3 + k;
        if (tt >= 0) acc = fmaf(w[d * 4 + k], xp[(size_t)tt * 4096 + d], acc);
    }
    float s = acc / (1.0f + __expf(-acc));
    xsb[idx] = f2bf(s);
}

// ---------------------------------------------------------------------------
// B/C projections from bf16 xs
// ---------------------------------------------------------------------------
__global__ __launch_bounds__(256) void bc_proj(const u16* __restrict__ xs,
                                               const float* __restrict__ Bw,
                                               const float* __restrict__ Cw,
                                               float* __restrict__ Bp,
                                               float* __restrict__ Cp) {
    __shared__ float row[DIN];
    const int bt = blockIdx.x;
    const u16* xr = xs + (size_t)bt * DIN;
    for (int i = threadIdx.x; i < DIN; i += 256) row[i] = bf2f(xr[i]);
    __syncthreads();
    const int wave = threadIdx.x >> 6;
    const int lane = threadIdx.x & 63;
    for (int o = wave; o < 32; o += 4) {
        const float* wrow = (o < 16) ? (Bw + (size_t)o * DIN) : (Cw + (size_t)(o - 16) * DIN);
        float s = 0.0f;
        for (int i = lane; i < DIN; i += 64) s = fmaf(row[i], wrow[i], s);
#pragma unroll
        for (int off = 32; off > 0; off >>= 1) s += __shfl_down(s, off);
        if (lane == 0) {
            if (o < 16) Bp[(size_t)bt * NST + o] = s;
            else        Cp[(size_t)bt * NST + (o - 16)] = s;
        }
    }
}

// ---------------------------------------------------------------------------
// Scan pass 1: per-chunk summaries (aprod = prod a, hout = local scan, h0=0)
// block = (b, c, db): 256 d-lanes; layouts [b][c][n][d] for coalescing.
// ---------------------------------------------------------------------------
__global__ __launch_bounds__(256) void scan1(const float* __restrict__ dt,
                                             const u16* __restrict__ xs,
                                             const float* __restrict__ Bp,
                                             const float* __restrict__ A_log,
                                             float* __restrict__ aprod,
                                             float* __restrict__ hout) {
    const int db = blockIdx.x & 7;
    const int c = (blockIdx.x >> 3) & (NC - 1);
    const int b = blockIdx.x >> 8;
    const int d = db * 256 + threadIdx.x;
    const int t0 = c * TC;

    __shared__ float Bs[TC * NST];
    for (int i = threadIdx.x; i < TC * NST; i += 256)
        Bs[i] = Bp[((size_t)b * LL + t0) * NST + i];
    __syncthreads();

    float Ac[NST];
#pragma unroll
    for (int n = 0; n < NST; ++n) Ac[n] = -__expf(A_log[d * NST + n]);

    float ap[NST], h[NST];
#pragma unroll
    for (int n = 0; n < NST; ++n) { ap[n] = 1.0f; h[n] = 0.0f; }

    const float* dtp = dt + ((size_t)b * LL + t0) * DIN + d;
    const u16*  xp  = xs + ((size_t)b * LL + t0) * DIN + d;

    for (int tt = 0; tt < TC; ++tt) {
        float dtv = dtp[(size_t)tt * DIN];
        float xv = bf2f(xp[(size_t)tt * DIN]);
        float bx = dtv * xv;
#pragma unroll
        for (int n = 0; n < NST; ++n) {
            float a = __expf(dtv * Ac[n]);
            ap[n] *= a;
            h[n] = fmaf(a, h[n], bx * Bs[tt * NST + n]);
        }
    }
#pragma unroll
    for (int n = 0; n < NST; ++n) {
        size_t idx = (((size_t)(b * NC + c) * NST) + n) * DIN + d;
        aprod[idx] = ap[n];
        hout[idx] = h[n];
    }
}

// ---------------------------------------------------------------------------
// Scan pass 2: cross-chunk combine. Thread per (b,n,d); 32 sequential chunks.
// ---------------------------------------------------------------------------
__global__ __launch_bounds__(256) void scan2(const float* __restrict__ aprod,
                                             const float* __restrict__ hout,
                                             float* __restrict__ hin) {
    const int gid = blockIdx.x * 256 + threadIdx.x;  // B*NST*DIN = 65536
    const int d = gid & (DIN - 1);
    const int n = (gid >> 11) & (NST - 1);
    const int b = gid >> 15;
    float h = 0.0f;
    for (int c = 0; c < NC; ++c) {
        size_t idx = (((size_t)(b * NC + c) * NST) + n) * DIN + d;
        hin[idx] = h;
        h = fmaf(aprod[idx], h, hout[idx]);
    }
}

// ---------------------------------------------------------------------------
// Scan pass 3: full scan within chunk from hin; fuse +D*xs, *silu(z), bf16 out
// ---------------------------------------------------------------------------
__global__ __launch_bounds__(256) void scan3(const float* __restrict__ dt,
                                             const u16* __restrict__ xs,
                                             const float* __restrict__ xz,
                                             const float* __restrict__ Bp,
                                             const float* __restrict__ Cp,
                                             const float* __restrict__ hin,
                                             const float* __restrict__ A_log,
                                             const float* __restrict__ Dp,
                                             u16* __restrict__ ybf) {
    const int db = blockIdx.x & 7;
    const int c = (blockIdx.x >> 3) & (NC - 1);
    const int b = blockIdx.x >> 8;
    const int d = db * 256 + threadIdx.x;
    const int t0 = c * TC;

    __shared__ float Bs[TC * NST];
    __shared__ float Cs[TC * NST];
    for (int i = threadIdx.x; i < TC * NST; i += 256) {
        Bs[i] = Bp[((size_t)b * LL + t0) * NST + i];
        Cs[i] = Cp[((size_t)b * LL + t0) * NST + i];
    }
    __syncthreads();

    float Ac[NST], h[NST];
#pragma unroll
    for (int n = 0; n < NST; ++n) {
        Ac[n] = -__expf(A_log[d * NST + n]);
        h[n] = hin[(((size_t)(b * NC + c) * NST) + n) * DIN + d];
    }
    const float Dv = Dp[d];

    const float* dtp = dt + ((size_t)b * LL + t0) * DIN + d;
    const u16*  xp  = xs + ((size_t)b * LL + t0) * DIN + d;
    const float* zp = xz + ((size_t)b * LL + t0) * 4096 + DIN + d;
    u16* yp = ybf + ((size_t)b * LL + t0) * DIN + d;

    for (int tt = 0; tt < TC; ++tt) {
        float dtv = dtp[(size_t)tt * DIN];
        float xv = bf2f(xp[(size_t)tt * DIN]);
        float zv = zp[(size_t)tt * 4096];
        float bx = dtv * xv;
        float y = 0.0f;
#pragma unroll
        for (int n = 0; n < NST; ++n) {
            float a = __expf(dtv * Ac[n]);
            h[n] = fmaf(a, h[n], bx * Bs[tt * NST + n]);
            y = fmaf(h[n], Cs[tt * NST + n], y);
        }
        y = fmaf(Dv, xv, y);
        float g = zv / (1.0f + __expf(-zv));
        yp[(size_t)tt * DIN] = f2bf(y * g);
    }
}

// ---------------------------------------------------------------------------
extern "C" void kernel_launch(void* const* d_in, const int* in_sizes, int n_in,
                              void* d_out, int out_size, void* d_ws, size_t ws_size,
                              hipStream_t stream) {
    const float* x          = (const float*)d_in[0];
    const float* in_proj_w  = (const float*)d_in[1];
    const float* conv_w     = (const float*)d_in[2];
    const float* conv_b     = (const float*)d_in[3];
    const float* dt_w       = (const float*)d_in[4];
    const float* dt_b       = (const float*)d_in[5];
    const float* B_proj_w   = (const float*)d_in[6];
    const float* C_proj_w   = (const float*)d_in[7];
    const float* A_log      = (const float*)d_in[8];
    const float* D_param    = (const float*)d_in[9];
    const float* out_proj_w = (const float*)d_in[10];
    float* out = (float*)d_out;
    float* ws  = (float*)d_ws;

    // f32 region (float offsets)
    float* xz    = ws;               // 16,777,216
    float* dtbuf = ws + 16777216;    //  8,388,608
    float* Bp    = ws + 25165824;    //     65,536
    float* Cp    = ws + 25231360;    //     65,536
    float* aprod = ws + 25296896;    //  2,097,152
    float* hout  = ws + 27394048;    //  2,097,152
    float* hin   = ws + 29491200;    //  2,097,152
    // bf16 region
    u16* bfbase  = (u16*)(ws + 31588352);
    u16* x_bf    = bfbase;               // 4,194,304
    u16* w1_bf   = bfbase + 4194304;     // 4,194,304
    u16* wdt_bf  = bfbase + 8388608;     // 4,194,304
    u16* wout_bf = bfbase + 12582912;    // 2,097,152
    u16* xs_bf   = bfbase + 14680064;    // 8,388,608
    u16* y_bf    = bfbase + 23068672;    // 8,388,608

    const int M = BB * LL;  // 4096

    // 0. bf16 conversions (x + 3 weight matrices)
    cvt_bf16<<<4194304 / 1024, 256, 0, stream>>>(x, x_bf);
    cvt_bf16<<<4194304 / 1024, 256, 0, stream>>>(in_proj_w, w1_bf);
    cvt_bf16<<<4194304 / 1024, 256, 0, stream>>>(dt_w, wdt_bf);
    cvt_bf16<<<2097152 / 1024, 256, 0, stream>>>(out_proj_w, wout_bf);

    // 1. xz = x @ in_proj_w^T   (M=4096, N=4096, K=1024)
    gemm_mfma<0><<<dim3(4096 / 128, M / 128), 256, 0, stream>>>(
        x_bf, w1_bf, xz, 4096, DMODEL, nullptr);

    // 2. causal depthwise conv + bias + silu -> xs (bf16)
    conv_silu<<<(BB * LL * DIN) / 256, 256, 0, stream>>>(xz, conv_w, conv_b, xs_bf);

    // 3. dt = softplus(xs @ dt_w^T + dt_b)   (M=4096, N=2048, K=2048)
    gemm_mfma<1><<<dim3(DIN / 128, M / 128), 256, 0, stream>>>(
        xs_bf, wdt_bf, dtbuf, DIN, DIN, dt_b);

    // 3b. Bp, Cp projections
    bc_proj<<<M, 256, 0, stream>>>(xs_bf, B_proj_w, C_proj_w, Bp, Cp);

    // 4. chunked selective scan
    scan1<<<BB * NC * 8, 256, 0, stream>>>(dtbuf, xs_bf, Bp, A_log, aprod, hout);
    scan2<<<(BB * NST * DIN) / 256, 256, 0, stream>>>(aprod, hout, hin);
    scan3<<<BB * NC * 8, 256, 0, stream>>>(dtbuf, xs_bf, xz, Bp, Cp, hin,
                                           A_log, D_param, y_bf);

    // 5. out = y_gated @ out_proj_w^T   (M=4096, N=1024, K=2048)
    gemm_mfma<0><<<dim3(DMODEL / 128, M / 128), 256, 0, stream>>>(
        y_bf, wout_bf, out, DMODEL, DIN, nullptr);
}

// Round 6
// 507.728 us; speedup vs baseline: 4.5296x; 1.1176x over previous
//
#include <hip/hip_runtime.h>
#include <cmath>

#define BB 2
#define LL 2048
#define DMODEL 1024
#define DIN 2048
#define NST 16
#define NC 32      // scan chunks
#define TC 64      // timesteps per chunk

typedef short short8 __attribute__((ext_vector_type(8)));
typedef float f32x4 __attribute__((ext_vector_type(4)));
typedef unsigned short u16;

__device__ __forceinline__ float bf2f(u16 u) {
    union { unsigned u; float f; } v; v.u = ((unsigned)u) << 16; return v.f;
}
__device__ __forceinline__ u16 f2bf(float f) {
    union { float f; unsigned u; } v; v.f = f;
    unsigned r = v.u + 0x7FFFu + ((v.u >> 16) & 1u);
    return (u16)(r >> 16);
}

// ---------------------------------------------------------------------------
// f32 -> bf16 conversion, 4 elements/thread
// ---------------------------------------------------------------------------
__global__ __launch_bounds__(256) void cvt_bf16(const float* __restrict__ in,
                                                u16* __restrict__ out) {
    int i = (blockIdx.x * 256 + threadIdx.x) * 4;
    float4 v = *reinterpret_cast<const float4*>(in + i);
    ushort4 o = {f2bf(v.x), f2bf(v.y), f2bf(v.z), f2bf(v.w)};
    *reinterpret_cast<ushort4*>(out + i) = o;
}

// ---------------------------------------------------------------------------
// bf16 MFMA GEMM (m97 structure): C[m,n] = sum_k A[m,k]*B[n,k], f32 out.
// 128x128 tile, BK=32, 256 thr (4 waves 2x2), 16x16x32 MFMA, 4x4 frags/wave.
// ---------------------------------------------------------------------------
__global__ __launch_bounds__(256) void gemm_mfma(const u16* __restrict__ A,
                                                 const u16* __restrict__ B,
                                                 float* __restrict__ C,
                                                 int N, int K) {
    __shared__ u16 As[128 * 32];
    __shared__ u16 Bs[128 * 32];
    const int tid = threadIdx.x;
    const int lane = tid & 63;
    const int wave = tid >> 6;
    const int bm = blockIdx.y * 128;
    const int bn = blockIdx.x * 128;
    const int wr = (wave >> 1) * 64;
    const int wc = (wave & 1) * 64;

    f32x4 acc[4][4];
#pragma unroll
    for (int i = 0; i < 4; ++i)
#pragma unroll
        for (int j = 0; j < 4; ++j) acc[i][j] = (f32x4){0.f, 0.f, 0.f, 0.f};

    const int frow = lane & 15;
    const int kch = (lane >> 4) * 8;

    for (int k0 = 0; k0 < K; k0 += 32) {
#pragma unroll
        for (int i = 0; i < 2; ++i) {
            int slot = i * 256 + tid;
            int r = slot >> 2;
            int c8 = (slot & 3) * 8;
            __builtin_amdgcn_global_load_lds(
                (const __attribute__((address_space(1))) void*)(A + (size_t)(bm + r) * K + k0 + c8),
                (__attribute__((address_space(3))) void*)(As + slot * 8), 16, 0, 0);
            __builtin_amdgcn_global_load_lds(
                (const __attribute__((address_space(1))) void*)(B + (size_t)(bn + r) * K + k0 + c8),
                (__attribute__((address_space(3))) void*)(Bs + slot * 8), 16, 0, 0);
        }
        __syncthreads();

        short8 af[4], bf[4];
#pragma unroll
        for (int mi = 0; mi < 4; ++mi)
            af[mi] = *reinterpret_cast<const short8*>(As + (wr + mi * 16 + frow) * 32 + kch);
#pragma unroll
        for (int ni = 0; ni < 4; ++ni)
            bf[ni] = *reinterpret_cast<const short8*>(Bs + (wc + ni * 16 + frow) * 32 + kch);
#pragma unroll
        for (int mi = 0; mi < 4; ++mi)
#pragma unroll
            for (int ni = 0; ni < 4; ++ni)
                acc[mi][ni] = __builtin_amdgcn_mfma_f32_16x16x32_bf16(
                    af[mi], bf[ni], acc[mi][ni], 0, 0, 0);
        __syncthreads();
    }

    const int crow0 = (lane >> 4) * 4;
    const int ccol = lane & 15;
#pragma unroll
    for (int mi = 0; mi < 4; ++mi)
#pragma unroll
        for (int ni = 0; ni < 4; ++ni) {
            const int col = bn + wc + ni * 16 + ccol;
#pragma unroll
            for (int r = 0; r < 4; ++r) {
                const int row = bm + wr + mi * 16 + crow0 + r;
                C[(size_t)row * N + col] = acc[mi][ni][r];
            }
        }
}

// ---------------------------------------------------------------------------
// dt GEMM fused with B/C projections. B-operand = [dt_w; B_proj; C_proj; pad]
// (2176 x 2048 bf16). Epilogue: col<2048 -> softplus(acc+bias) -> dtbuf;
// 2048..2063 -> Bp; 2064..2079 -> Cp; >=2080 discarded (pad rows poisoned ok).
// ---------------------------------------------------------------------------
__global__ __launch_bounds__(256) void gemm_dtbc(const u16* __restrict__ A,
                                                 const u16* __restrict__ B,
                                                 float* __restrict__ dtbuf,
                                                 float* __restrict__ Bp,
                                                 float* __restrict__ Cp,
                                                 const float* __restrict__ bias) {
    const int K = DIN;
    __shared__ u16 As[128 * 32];
    __shared__ u16 Bs[128 * 32];
    const int tid = threadIdx.x;
    const int lane = tid & 63;
    const int wave = tid >> 6;
    const int bm = blockIdx.y * 128;
    const int bn = blockIdx.x * 128;
    const int wr = (wave >> 1) * 64;
    const int wc = (wave & 1) * 64;

    f32x4 acc[4][4];
#pragma unroll
    for (int i = 0; i < 4; ++i)
#pragma unroll
        for (int j = 0; j < 4; ++j) acc[i][j] = (f32x4){0.f, 0.f, 0.f, 0.f};

    const int frow = lane & 15;
    const int kch = (lane >> 4) * 8;

    for (int k0 = 0; k0 < K; k0 += 32) {
#pragma unroll
        for (int i = 0; i < 2; ++i) {
            int slot = i * 256 + tid;
            int r = slot >> 2;
            int c8 = (slot & 3) * 8;
            __builtin_amdgcn_global_load_lds(
                (const __attribute__((address_space(1))) void*)(A + (size_t)(bm + r) * K + k0 + c8),
                (__attribute__((address_space(3))) void*)(As + slot * 8), 16, 0, 0);
            __builtin_amdgcn_global_load_lds(
                (const __attribute__((address_space(1))) void*)(B + (size_t)(bn + r) * K + k0 + c8),
                (__attribute__((address_space(3))) void*)(Bs + slot * 8), 16, 0, 0);
        }
        __syncthreads();

        short8 af[4], bf[4];
#pragma unroll
        for (int mi = 0; mi < 4; ++mi)
            af[mi] = *reinterpret_cast<const short8*>(As + (wr + mi * 16 + frow) * 32 + kch);
#pragma unroll
        for (int ni = 0; ni < 4; ++ni)
            bf[ni] = *reinterpret_cast<const short8*>(Bs + (wc + ni * 16 + frow) * 32 + kch);
#pragma unroll
        for (int mi = 0; mi < 4; ++mi)
#pragma unroll
            for (int ni = 0; ni < 4; ++ni)
                acc[mi][ni] = __builtin_amdgcn_mfma_f32_16x16x32_bf16(
                    af[mi], bf[ni], acc[mi][ni], 0, 0, 0);
        __syncthreads();
    }

    const int crow0 = (lane >> 4) * 4;
    const int ccol = lane & 15;
#pragma unroll
    for (int mi = 0; mi < 4; ++mi)
#pragma unroll
        for (int ni = 0; ni < 4; ++ni) {
            const int col = bn + wc + ni * 16 + ccol;
            if (col >= DIN + 32) continue;
            float bv = (col < DIN) ? bias[col] : 0.f;
#pragma unroll
            for (int r = 0; r < 4; ++r) {
                const int row = bm + wr + mi * 16 + crow0 + r;
                float v = acc[mi][ni][r];
                if (col < DIN) {
                    v += bv;
                    v = (v > 20.0f) ? v : log1pf(__expf(v));
                    dtbuf[(size_t)row * DIN + col] = v;
                } else if (col < DIN + 16) {
                    Bp[(size_t)row * NST + (col - DIN)] = v;
                } else {
                    Cp[(size_t)row * NST + (col - DIN - 16)] = v;
                }
            }
        }
}

// ---------------------------------------------------------------------------
// Depthwise causal conv (K=4) + bias + SiLU -> xs (bf16)
// ---------------------------------------------------------------------------
__global__ __launch_bounds__(256) void conv_silu(const float* __restrict__ xz,
                                                 const float* __restrict__ w,
                                                 const float* __restrict__ b,
                                                 u16* __restrict__ xsb) {
    int idx = blockIdx.x * 256 + threadIdx.x;   // B*L*DIN
    int d = idx & (DIN - 1);
    int t = (idx >> 11) & (LL - 1);
    int bb = idx >> 22;
    const float* xp = xz + (size_t)bb * LL * 4096;
    float acc = b[d];
#pragma unroll
    for (int k = 0; k < 4; ++k) {
        int tt = t - 3 + k;
        if (tt >= 0) acc = fmaf(w[d * 4 + k], xp[(size_t)tt * 4096 + d], acc);
    }
    float s = acc / (1.0f + __expf(-acc));
    xsb[idx] = f2bf(s);
}

// ---------------------------------------------------------------------------
// Scan pass 1: per-chunk summaries (aprod = prod a, hout = local scan, h0=0)
// ---------------------------------------------------------------------------
__global__ __launch_bounds__(256) void scan1(const float* __restrict__ dt,
                                             const u16* __restrict__ xs,
                                             const float* __restrict__ Bp,
                                             const float* __restrict__ A_log,
                                             float* __restrict__ aprod,
                                             float* __restrict__ hout) {
    const int db = blockIdx.x & 7;
    const int c = (blockIdx.x >> 3) & (NC - 1);
    const int b = blockIdx.x >> 8;
    const int d = db * 256 + threadIdx.x;
    const int t0 = c * TC;

    __shared__ float Bs[TC * NST];
    for (int i = threadIdx.x; i < TC * NST; i += 256)
        Bs[i] = Bp[((size_t)b * LL + t0) * NST + i];
    __syncthreads();

    float Ac[NST];
#pragma unroll
    for (int n = 0; n < NST; ++n) Ac[n] = -__expf(A_log[d * NST + n]);

    float ap[NST], h[NST];
#pragma unroll
    for (int n = 0; n < NST; ++n) { ap[n] = 1.0f; h[n] = 0.0f; }

    const float* dtp = dt + ((size_t)b * LL + t0) * DIN + d;
    const u16*  xp  = xs + ((size_t)b * LL + t0) * DIN + d;

    for (int tt = 0; tt < TC; ++tt) {
        float dtv = dtp[(size_t)tt * DIN];
        float xv = bf2f(xp[(size_t)tt * DIN]);
        float bx = dtv * xv;
#pragma unroll
        for (int n = 0; n < NST; ++n) {
            float a = __expf(dtv * Ac[n]);
            ap[n] *= a;
            h[n] = fmaf(a, h[n], bx * Bs[tt * NST + n]);
        }
    }
#pragma unroll
    for (int n = 0; n < NST; ++n) {
        size_t idx = (((size_t)(b * NC + c) * NST) + n) * DIN + d;
        aprod[idx] = ap[n];
        hout[idx] = h[n];
    }
}

// ---------------------------------------------------------------------------
// Scan pass 2: cross-chunk combine. Thread per (b,n,d); 32 sequential chunks.
// ---------------------------------------------------------------------------
__global__ __launch_bounds__(256) void scan2(const float* __restrict__ aprod,
                                             const float* __restrict__ hout,
                                             float* __restrict__ hin) {
    const int gid = blockIdx.x * 256 + threadIdx.x;  // B*NST*DIN
    const int d = gid & (DIN - 1);
    const int n = (gid >> 11) & (NST - 1);
    const int b = gid >> 15;
    float h = 0.0f;
    for (int c = 0; c < NC; ++c) {
        size_t idx = (((size_t)(b * NC + c) * NST) + n) * DIN + d;
        hin[idx] = h;
        h = fmaf(aprod[idx], h, hout[idx]);
    }
}

// ---------------------------------------------------------------------------
// Scan pass 3: full scan within chunk from hin; fuse +D*xs, *silu(z), bf16 out
// ---------------------------------------------------------------------------
__global__ __launch_bounds__(256) void scan3(const float* __restrict__ dt,
                                             const u16* __restrict__ xs,
                                             const float* __restrict__ xz,
                                             const float* __restrict__ Bp,
                                             const float* __restrict__ Cp,
                                             const float* __restrict__ hin,
                                             const float* __restrict__ A_log,
                                             const float* __restrict__ Dp,
                                             u16* __restrict__ ybf) {
    const int db = blockIdx.x & 7;
    const int c = (blockIdx.x >> 3) & (NC - 1);
    const int b = blockIdx.x >> 8;
    const int d = db * 256 + threadIdx.x;
    const int t0 = c * TC;

    __shared__ float Bs[TC * NST];
    __shared__ float Cs[TC * NST];
    for (int i = threadIdx.x; i < TC * NST; i += 256) {
        Bs[i] = Bp[((size_t)b * LL + t0) * NST + i];
        Cs[i] = Cp[((size_t)b * LL + t0) * NST + i];
    }
    __syncthreads();

    float Ac[NST], h[NST];
#pragma unroll
    for (int n = 0; n < NST; ++n) {
        Ac[n] = -__expf(A_log[d * NST + n]);
        h[n] = hin[(((size_t)(b * NC + c) * NST) + n) * DIN + d];
    }
    const float Dv = Dp[d];

    const float* dtp = dt + ((size_t)b * LL + t0) * DIN + d;
    const u16*  xp  = xs + ((size_t)b * LL + t0) * DIN + d;
    const float* zp = xz + ((size_t)b * LL + t0) * 4096 + DIN + d;
    u16* yp = ybf + ((size_t)b * LL + t0) * DIN + d;

    for (int tt = 0; tt < TC; ++tt) {
        float dtv = dtp[(size_t)tt * DIN];
        float xv = bf2f(xp[(size_t)tt * DIN]);
        float zv = zp[(size_t)tt * 4096];
        float bx = dtv * xv;
        float y = 0.0f;
#pragma unroll
        for (int n = 0; n < NST; ++n) {
            float a = __expf(dtv * Ac[n]);
            h[n] = fmaf(a, h[n], bx * Bs[tt * NST + n]);
            y = fmaf(h[n], Cs[tt * NST + n], y);
        }
        y = fmaf(Dv, xv, y);
        float g = zv / (1.0f + __expf(-zv));
        yp[(size_t)tt * DIN] = f2bf(y * g);
    }
}

// ---------------------------------------------------------------------------
extern "C" void kernel_launch(void* const* d_in, const int* in_sizes, int n_in,
                              void* d_out, int out_size, void* d_ws, size_t ws_size,
                              hipStream_t stream) {
    const float* x          = (const float*)d_in[0];
    const float* in_proj_w  = (const float*)d_in[1];
    const float* conv_w     = (const float*)d_in[2];
    const float* conv_b     = (const float*)d_in[3];
    const float* dt_w       = (const float*)d_in[4];
    const float* dt_b       = (const float*)d_in[5];
    const float* B_proj_w   = (const float*)d_in[6];
    const float* C_proj_w   = (const float*)d_in[7];
    const float* A_log      = (const float*)d_in[8];
    const float* D_param    = (const float*)d_in[9];
    const float* out_proj_w = (const float*)d_in[10];
    float* out = (float*)d_out;
    float* ws  = (float*)d_ws;

    // f32 region (float offsets)
    float* xz    = ws;               // 16,777,216
    float* dtbuf = ws + 16777216;    //  8,388,608
    float* Bp    = ws + 25165824;    //     65,536
    float* Cp    = ws + 25231360;    //     65,536
    float* aprod = ws + 25296896;    //  2,097,152
    float* hout  = ws + 27394048;    //  2,097,152
    float* hin   = ws + 29491200;    //  2,097,152
    // bf16 region
    u16* bfbase   = (u16*)(ws + 31588352);
    u16* x_bf     = bfbase;                 // 4,194,304 (dead after gemm1)
    u16* w1_bf    = bfbase + 4194304;       // 4,194,304 (dead after gemm1)
    u16* y_bf     = bfbase;                 // 8,388,608 (aliases x_bf+w1_bf)
    u16* wdtbc_bf = bfbase + 8388608;       // 2176*2048 = 4,456,448
    u16* wout_bf  = bfbase + 12845056;      // 2,097,152
    u16* xs_bf    = bfbase + 14942208;      // 8,388,608

    const int M = BB * LL;  // 4096

    // 0. bf16 conversions: x, in_proj_w, [dt_w|B_proj|C_proj], out_proj_w
    cvt_bf16<<<4194304 / 1024, 256, 0, stream>>>(x, x_bf);
    cvt_bf16<<<4194304 / 1024, 256, 0, stream>>>(in_proj_w, w1_bf);
    cvt_bf16<<<4194304 / 1024, 256, 0, stream>>>(dt_w, wdtbc_bf);
    cvt_bf16<<<32768 / 1024, 256, 0, stream>>>(B_proj_w, wdtbc_bf + (size_t)DIN * DIN);
    cvt_bf16<<<32768 / 1024, 256, 0, stream>>>(C_proj_w, wdtbc_bf + (size_t)(DIN + 16) * DIN);
    cvt_bf16<<<2097152 / 1024, 256, 0, stream>>>(out_proj_w, wout_bf);

    // 1. xz = x @ in_proj_w^T   (M=4096, N=4096, K=1024)
    gemm_mfma<<<dim3(4096 / 128, M / 128), 256, 0, stream>>>(
        x_bf, w1_bf, xz, 4096, DMODEL);

    // 2. causal depthwise conv + bias + silu -> xs (bf16)
    conv_silu<<<(BB * LL * DIN) / 256, 256, 0, stream>>>(xz, conv_w, conv_b, xs_bf);

    // 3. dt/Bp/Cp fused GEMM  (M=4096, N=2176, K=2048)
    gemm_dtbc<<<dim3(17, M / 128), 256, 0, stream>>>(
        xs_bf, wdtbc_bf, dtbuf, Bp, Cp, dt_b);

    // 4. chunked selective scan
    scan1<<<BB * NC * 8, 256, 0, stream>>>(dtbuf, xs_bf, Bp, A_log, aprod, hout);
    scan2<<<(BB * NST * DIN) / 256, 256, 0, stream>>>(aprod, hout, hin);
    scan3<<<BB * NC * 8, 256, 0, stream>>>(dtbuf, xs_bf, xz, Bp, Cp, hin,
                                           A_log, D_param, y_bf);

    // 5. out = y_gated @ out_proj_w^T   (M=4096, N=1024, K=2048)
    gemm_mfma<<<dim3(DMODEL / 128, M / 128), 256, 0, stream>>>(
        y_bf, wout_bf, out, DMODEL, DIN);
}

// Round 7
// 491.373 us; speedup vs baseline: 4.6803x; 1.0333x over previous
//
#include <hip/hip_runtime.h>
#include <cmath>

#define BB 2
#define LL 2048
#define DMODEL 1024
#define DIN 2048
#define NST 16
#define NC 32      // scan chunks
#define TC 64      // timesteps per chunk

typedef short short8 __attribute__((ext_vector_type(8)));
typedef float f32x4 __attribute__((ext_vector_type(4)));
typedef unsigned short u16;

__device__ __forceinline__ float bf2f(u16 u) {
    union { unsigned u; float f; } v; v.u = ((unsigned)u) << 16; return v.f;
}
__device__ __forceinline__ u16 f2bf(float f) {
    union { float f; unsigned u; } v; v.f = f;
    unsigned r = v.u + 0x7FFFu + ((v.u >> 16) & 1u);
    return (u16)(r >> 16);
}

// ---------------------------------------------------------------------------
// f32 -> bf16 conversion, 4 elements/thread
// ---------------------------------------------------------------------------
__global__ __launch_bounds__(256) void cvt_bf16(const float* __restrict__ in,
                                                u16* __restrict__ out) {
    int i = (blockIdx.x * 256 + threadIdx.x) * 4;
    float4 v = *reinterpret_cast<const float4*>(in + i);
    ushort4 o = {f2bf(v.x), f2bf(v.y), f2bf(v.z), f2bf(v.w)};
    *reinterpret_cast<ushort4*>(out + i) = o;
}

// ---------------------------------------------------------------------------
// 256x256 8-phase bf16 MFMA GEMM (T2 swizzle + T3/T4 counted vmcnt + T5).
// C[m,n] = sum_k A[m,k]*B[n,k]. 512 thr, 8 waves (2M x 4N, interleaved frags).
// BK=64, LDS = 2 dbuf x ([256][64] A + [256][64] B) bf16 = 128 KiB.
// Swizzle (u16 units): u ^= ((u>>7)&7)<<3  (row bits 1-3 -> k bits 3-5),
// applied to pre-swizzled global source at stage and to ds_read addresses.
// Per K-tile: 4 quadrant phases (mh,nh) = (0,0),(0,1),(1,0),(1,1).
// Stage stream: ph0->B0(t+1), ph1->B1(t+1), ph2->A1(t+1), ph3->A0(t+2).
// vmcnt(6) at ph1-end, vmcnt(4) at ph3-end (tail: 0 / 2).
// EPI 0: C[row*N+col]; EPI 1: dt/Bp/Cp routing with softplus+bias.
// ---------------------------------------------------------------------------
template <int KDIM, int EPI>
__global__ __launch_bounds__(512, 2) void gemm256(const u16* __restrict__ A,
                                                  const u16* __restrict__ B,
                                                  float* __restrict__ C, int N,
                                                  const float* __restrict__ bias,
                                                  float* __restrict__ Bp,
                                                  float* __restrict__ Cp) {
    constexpr int NT = KDIM / 64;
    __shared__ u16 lds[65536];   // 128 KiB
    const int tid = threadIdx.x;
    const int lane = tid & 63;
    const int wid = tid >> 6;        // 0..7
    const int wr16 = (wid >> 2) * 16;  // M interleave: frag f rows = f*32 + wr16
    const int wc16 = (wid & 3) * 16;   // N interleave: frag j cols = j*64 + wc16
    const int bm = blockIdx.y * 256;
    const int bn = blockIdx.x * 256;
    const int fr = lane & 15;
    const int kg8 = (lane >> 4) * 8;

    u16* const At0 = lds;
    u16* const At1 = lds + 16384;
    u16* const Bt0 = lds + 32768;
    u16* const Bt1 = lds + 49152;

    f32x4 acc[8][4];
#pragma unroll
    for (int f = 0; f < 8; ++f)
#pragma unroll
        for (int j = 0; j < 4; ++j) acc[f][j] = (f32x4){0.f, 0.f, 0.f, 0.f};

    // stage one 128-row half-tile (2 x global_load_lds of 16B per thread),
    // pre-swizzled global source so LDS reads can use the same XOR.
    auto STAGE = [&](const u16* __restrict__ G, int base_row, int kt,
                     u16* dst_tile, int half) {
#pragma unroll
        for (int rr = 0; rr < 2; ++rr) {
            int c = half * 1024 + rr * 512 + tid;       // 16B chunk in tile
            int cs = c ^ ((c >> 4) & 7);                // inverse swizzle (involution)
            __builtin_amdgcn_global_load_lds(
                (const __attribute__((address_space(1))) void*)(
                    G + (size_t)(base_row + (cs >> 3)) * KDIM + kt + ((cs & 7) << 3)),
                (__attribute__((address_space(3))) void*)(dst_tile + c * 8), 16, 0, 0);
        }
    };
    auto LDSW = [&](const u16* tile, int row, int k) -> short8 {
        int u = row * 64 + k;
        u ^= ((u >> 7) & 7) << 3;
        return *reinterpret_cast<const short8*>(tile + u);
    };

    // ---- prologue: t0:{A0,B0,B1,A1}, t1:A0 ; vmcnt(4) proves t0:{A0,B0,B1}
    STAGE(A, bm, 0, At0, 0);
    STAGE(B, bn, 0, Bt0, 0);
    STAGE(B, bn, 0, Bt0, 1);
    STAGE(A, bm, 0, At0, 1);
    if (NT > 1) STAGE(A, bm, 64, At1, 0);
    asm volatile("s_waitcnt vmcnt(4)" ::: "memory");
    __builtin_amdgcn_s_barrier();

    short8 af[4][2], bf[2][2];
#pragma unroll 1
    for (int t = 0; t < NT; ++t) {
        const int buf = t & 1;
        u16* const Ac = buf ? At1 : At0;
        u16* const Bc = buf ? Bt1 : Bt0;
        u16* const An = buf ? At0 : At1;
        u16* const Bn = buf ? Bt0 : Bt1;
        const int kn = (t + 1) * 64;

        // ---- ph0: quadrant (mh0, nh0) — reads A-half0 + B-half0
#pragma unroll
        for (int f = 0; f < 4; ++f)
#pragma unroll
            for (int ks = 0; ks < 2; ++ks)
                af[f][ks] = LDSW(Ac, f * 32 + wr16 + fr, ks * 32 + kg8);
#pragma unroll
        for (int j = 0; j < 2; ++j)
#pragma unroll
            for (int ks = 0; ks < 2; ++ks)
                bf[j][ks] = LDSW(Bc, j * 64 + wc16 + fr, ks * 32 + kg8);
        if (t + 1 < NT) STAGE(B, bn, kn, Bn, 0);
        __builtin_amdgcn_s_barrier();
        __builtin_amdgcn_s_setprio(1);
#pragma unroll
        for (int ks = 0; ks < 2; ++ks)
#pragma unroll
            for (int f = 0; f < 4; ++f)
#pragma unroll
                for (int j = 0; j < 2; ++j)
                    acc[f][j] = __builtin_amdgcn_mfma_f32_16x16x32_bf16(
                        af[f][ks], bf[j][ks], acc[f][j], 0, 0, 0);
        __builtin_amdgcn_s_setprio(0);
        __builtin_amdgcn_s_barrier();

        // ---- ph1: quadrant (mh0, nh1) — af reuse, read B-half1
#pragma unroll
        for (int j = 0; j < 2; ++j)
#pragma unroll
            for (int ks = 0; ks < 2; ++ks)
                bf[j][ks] = LDSW(Bc, 128 + j * 64 + wc16 + fr, ks * 32 + kg8);
        if (t + 1 < NT) STAGE(B, bn, kn, Bn, 1);
        __builtin_amdgcn_s_barrier();
        __builtin_amdgcn_s_setprio(1);
#pragma unroll
        for (int ks = 0; ks < 2; ++ks)
#pragma unroll
            for (int f = 0; f < 4; ++f)
#pragma unroll
                for (int j = 0; j < 2; ++j)
                    acc[f][j + 2] = __builtin_amdgcn_mfma_f32_16x16x32_bf16(
                        af[f][ks], bf[j][ks], acc[f][j + 2], 0, 0, 0);
        __builtin_amdgcn_s_setprio(0);
        if (t + 1 < NT) { asm volatile("s_waitcnt vmcnt(6)" ::: "memory"); }
        else            { asm volatile("s_waitcnt vmcnt(0)" ::: "memory"); }
        __builtin_amdgcn_s_barrier();

        // ---- ph2: quadrant (mh1, nh0) — read A-half1 + B-half0 (re-read)
#pragma unroll
        for (int f = 0; f < 4; ++f)
#pragma unroll
            for (int ks = 0; ks < 2; ++ks)
                af[f][ks] = LDSW(Ac, 128 + f * 32 + wr16 + fr, ks * 32 + kg8);
#pragma unroll
        for (int j = 0; j < 2; ++j)
#pragma unroll
            for (int ks = 0; ks < 2; ++ks)
                bf[j][ks] = LDSW(Bc, j * 64 + wc16 + fr, ks * 32 + kg8);
        if (t + 1 < NT) STAGE(A, bm, kn, An, 1);
        __builtin_amdgcn_s_barrier();
        __builtin_amdgcn_s_setprio(1);
#pragma unroll
        for (int ks = 0; ks < 2; ++ks)
#pragma unroll
            for (int f = 0; f < 4; ++f)
#pragma unroll
                for (int j = 0; j < 2; ++j)
                    acc[f + 4][j] = __builtin_amdgcn_mfma_f32_16x16x32_bf16(
                        af[f][ks], bf[j][ks], acc[f + 4][j], 0, 0, 0);
        __builtin_amdgcn_s_setprio(0);
        __builtin_amdgcn_s_barrier();

        // ---- ph3: quadrant (mh1, nh1) — af reuse, read B-half1; stage t+2:A0
#pragma unroll
        for (int j = 0; j < 2; ++j)
#pragma unroll
            for (int ks = 0; ks < 2; ++ks)
                bf[j][ks] = LDSW(Bc, 128 + j * 64 + wc16 + fr, ks * 32 + kg8);
        if (t + 2 < NT) STAGE(A, bm, kn + 64, Ac, 0);  // current A0 dead since ph0
        __builtin_amdgcn_s_barrier();
        __builtin_amdgcn_s_setprio(1);
#pragma unroll
        for (int ks = 0; ks < 2; ++ks)
#pragma unroll
            for (int f = 0; f < 4; ++f)
#pragma unroll
                for (int j = 0; j < 2; ++j)
                    acc[f + 4][j + 2] = __builtin_amdgcn_mfma_f32_16x16x32_bf16(
                        af[f][ks], bf[j][ks], acc[f + 4][j + 2], 0, 0, 0);
        __builtin_amdgcn_s_setprio(0);
        if (t + 2 < NT)      { asm volatile("s_waitcnt vmcnt(4)" ::: "memory"); }
        else if (t + 1 < NT) { asm volatile("s_waitcnt vmcnt(2)" ::: "memory"); }
        else                 { asm volatile("s_waitcnt vmcnt(0)" ::: "memory"); }
        __builtin_amdgcn_s_barrier();
    }

    // ---- epilogue
    const int crow0 = (lane >> 4) * 4;
    const int ccol = lane & 15;
#pragma unroll
    for (int f = 0; f < 8; ++f) {
#pragma unroll
        for (int j = 0; j < 4; ++j) {
            const int col = bn + j * 64 + wc16 + ccol;
            if (EPI == 1 && col >= DIN + 32) continue;
            float bv = (EPI == 1 && col < DIN) ? bias[col] : 0.f;
#pragma unroll
            for (int r = 0; r < 4; ++r) {
                const int row = bm + f * 32 + wr16 + crow0 + r;
                float v = acc[f][j][r];
                if (EPI == 1) {
                    if (col < DIN) {
                        v += bv;
                        v = (v > 20.0f) ? v : log1pf(__expf(v));
                        C[(size_t)row * N + col] = v;
                    } else if (col < DIN + 16) {
                        Bp[(size_t)row * NST + (col - DIN)] = v;
                    } else {
                        Cp[(size_t)row * NST + (col - DIN - 16)] = v;
                    }
                } else {
                    C[(size_t)row * N + col] = v;
                }
            }
        }
    }
}

// ---------------------------------------------------------------------------
// Depthwise causal conv (K=4) + bias + SiLU -> xs (bf16)
// ---------------------------------------------------------------------------
__global__ __launch_bounds__(256) void conv_silu(const float* __restrict__ xz,
                                                 const float* __restrict__ w,
                                                 const float* __restrict__ b,
                                                 u16* __restrict__ xsb) {
    int idx = blockIdx.x * 256 + threadIdx.x;   // B*L*DIN
    int d = idx & (DIN - 1);
    int t = (idx >> 11) & (LL - 1);
    int bb = idx >> 22;
    const float* xp = xz + (size_t)bb * LL * 4096;
    float acc = b[d];
#pragma unroll
    for (int k = 0; k < 4; ++k) {
        int tt = t - 3 + k;
        if (tt >= 0) acc = fmaf(w[d * 4 + k], xp[(size_t)tt * 4096 + d], acc);
    }
    float s = acc / (1.0f + __expf(-acc));
    xsb[idx] = f2bf(s);
}

// ---------------------------------------------------------------------------
// Scan pass 1: per-chunk summaries (aprod = prod a, hout = local scan, h0=0)
// ---------------------------------------------------------------------------
__global__ __launch_bounds__(256) void scan1(const float* __restrict__ dt,
                                             const u16* __restrict__ xs,
                                             const float* __restrict__ Bp,
                                             const float* __restrict__ A_log,
                                             float* __restrict__ aprod,
                                             float* __restrict__ hout) {
    const int db = blockIdx.x & 7;
    const int c = (blockIdx.x >> 3) & (NC - 1);
    const int b = blockIdx.x >> 8;
    const int d = db * 256 + threadIdx.x;
    const int t0 = c * TC;

    __shared__ float Bs[TC * NST];
    for (int i = threadIdx.x; i < TC * NST; i += 256)
        Bs[i] = Bp[((size_t)b * LL + t0) * NST + i];
    __syncthreads();

    float Ac[NST];
#pragma unroll
    for (int n = 0; n < NST; ++n) Ac[n] = -__expf(A_log[d * NST + n]);

    float ap[NST], h[NST];
#pragma unroll
    for (int n = 0; n < NST; ++n) { ap[n] = 1.0f; h[n] = 0.0f; }

    const float* dtp = dt + ((size_t)b * LL + t0) * DIN + d;
    const u16*  xp  = xs + ((size_t)b * LL + t0) * DIN + d;

    for (int tt = 0; tt < TC; ++tt) {
        float dtv = dtp[(size_t)tt * DIN];
        float xv = bf2f(xp[(size_t)tt * DIN]);
        float bx = dtv * xv;
#pragma unroll
        for (int n = 0; n < NST; ++n) {
            float a = __expf(dtv * Ac[n]);
            ap[n] *= a;
            h[n] = fmaf(a, h[n], bx * Bs[tt * NST + n]);
        }
    }
#pragma unroll
    for (int n = 0; n < NST; ++n) {
        size_t idx = (((size_t)(b * NC + c) * NST) + n) * DIN + d;
        aprod[idx] = ap[n];
        hout[idx] = h[n];
    }
}

// ---------------------------------------------------------------------------
// Scan pass 2: cross-chunk combine. Thread per (b,n,d); 32 sequential chunks.
// ---------------------------------------------------------------------------
__global__ __launch_bounds__(256) void scan2(const float* __restrict__ aprod,
                                             const float* __restrict__ hout,
                                             float* __restrict__ hin) {
    const int gid = blockIdx.x * 256 + threadIdx.x;  // B*NST*DIN
    const int d = gid & (DIN - 1);
    const int n = (gid >> 11) & (NST - 1);
    const int b = gid >> 15;
    float h = 0.0f;
    for (int c = 0; c < NC; ++c) {
        size_t idx = (((size_t)(b * NC + c) * NST) + n) * DIN + d;
        hin[idx] = h;
        h = fmaf(aprod[idx], h, hout[idx]);
    }
}

// ---------------------------------------------------------------------------
// Scan pass 3: full scan within chunk from hin; fuse +D*xs, *silu(z), bf16 out
// ---------------------------------------------------------------------------
__global__ __launch_bounds__(256) void scan3(const float* __restrict__ dt,
                                             const u16* __restrict__ xs,
                                             const float* __restrict__ xz,
                                             const float* __restrict__ Bp,
                                             const float* __restrict__ Cp,
                                             const float* __restrict__ hin,
                                             const float* __restrict__ A_log,
                                             const float* __restrict__ Dp,
                                             u16* __restrict__ ybf) {
    const int db = blockIdx.x & 7;
    const int c = (blockIdx.x >> 3) & (NC - 1);
    const int b = blockIdx.x >> 8;
    const int d = db * 256 + threadIdx.x;
    const int t0 = c * TC;

    __shared__ float Bs[TC * NST];
    __shared__ float Cs[TC * NST];
    for (int i = threadIdx.x; i < TC * NST; i += 256) {
        Bs[i] = Bp[((size_t)b * LL + t0) * NST + i];
        Cs[i] = Cp[((size_t)b * LL + t0) * NST + i];
    }
    __syncthreads();

    float Ac[NST], h[NST];
#pragma unroll
    for (int n = 0; n < NST; ++n) {
        Ac[n] = -__expf(A_log[d * NST + n]);
        h[n] = hin[(((size_t)(b * NC + c) * NST) + n) * DIN + d];
    }
    const float Dv = Dp[d];

    const float* dtp = dt + ((size_t)b * LL + t0) * DIN + d;
    const u16*  xp  = xs + ((size_t)b * LL + t0) * DIN + d;
    const float* zp = xz + ((size_t)b * LL + t0) * 4096 + DIN + d;
    u16* yp = ybf + ((size_t)b * LL + t0) * DIN + d;

    for (int tt = 0; tt < TC; ++tt) {
        float dtv = dtp[(size_t)tt * DIN];
        float xv = bf2f(xp[(size_t)tt * DIN]);
        float zv = zp[(size_t)tt * 4096];
        float bx = dtv * xv;
        float y = 0.0f;
#pragma unroll
        for (int n = 0; n < NST; ++n) {
            float a = __expf(dtv * Ac[n]);
            h[n] = fmaf(a, h[n], bx * Bs[tt * NST + n]);
            y = fmaf(h[n], Cs[tt * NST + n], y);
        }
        y = fmaf(Dv, xv, y);
        float g = zv / (1.0f + __expf(-zv));
        yp[(size_t)tt * DIN] = f2bf(y * g);
    }
}

// ---------------------------------------------------------------------------
extern "C" void kernel_launch(void* const* d_in, const int* in_sizes, int n_in,
                              void* d_out, int out_size, void* d_ws, size_t ws_size,
                              hipStream_t stream) {
    const float* x          = (const float*)d_in[0];
    const float* in_proj_w  = (const float*)d_in[1];
    const float* conv_w     = (const float*)d_in[2];
    const float* conv_b     = (const float*)d_in[3];
    const float* dt_w       = (const float*)d_in[4];
    const float* dt_b       = (const float*)d_in[5];
    const float* B_proj_w   = (const float*)d_in[6];
    const float* C_proj_w   = (const float*)d_in[7];
    const float* A_log      = (const float*)d_in[8];
    const float* D_param    = (const float*)d_in[9];
    const float* out_proj_w = (const float*)d_in[10];
    float* out = (float*)d_out;
    float* ws  = (float*)d_ws;

    // f32 region (float offsets)
    float* xz    = ws;               // 16,777,216
    float* dtbuf = ws + 16777216;    //  8,388,608
    float* Bp    = ws + 25165824;    //     65,536
    float* Cp    = ws + 25231360;    //     65,536
    float* aprod = ws + 25296896;    //  2,097,152
    float* hout  = ws + 27394048;    //  2,097,152
    float* hin   = ws + 29491200;    //  2,097,152
    // bf16 region
    u16* bfbase   = (u16*)(ws + 31588352);
    u16* x_bf     = bfbase;                 // 4,194,304 (dead after gemm1)
    u16* w1_bf    = bfbase + 4194304;       // 4,194,304 (dead after gemm1)
    u16* y_bf     = bfbase;                 // 8,388,608 (aliases x_bf+w1_bf)
    u16* wdtbc_bf = bfbase + 8388608;       // 2304*2048 = 4,718,592 (pad rows garbage)
    u16* wout_bf  = bfbase + 13107200;      // 2,097,152
    u16* xs_bf    = bfbase + 15204352;      // 8,388,608

    const int M = BB * LL;  // 4096

    // 0. bf16 conversions: x, in_proj_w, [dt_w|B_proj|C_proj|pad], out_proj_w
    cvt_bf16<<<4194304 / 1024, 256, 0, stream>>>(x, x_bf);
    cvt_bf16<<<4194304 / 1024, 256, 0, stream>>>(in_proj_w, w1_bf);
    cvt_bf16<<<4194304 / 1024, 256, 0, stream>>>(dt_w, wdtbc_bf);
    cvt_bf16<<<32768 / 1024, 256, 0, stream>>>(B_proj_w, wdtbc_bf + (size_t)DIN * DIN);
    cvt_bf16<<<32768 / 1024, 256, 0, stream>>>(C_proj_w, wdtbc_bf + (size_t)(DIN + 16) * DIN);
    cvt_bf16<<<2097152 / 1024, 256, 0, stream>>>(out_proj_w, wout_bf);

    // 1. xz = x @ in_proj_w^T   (M=4096, N=4096, K=1024)
    gemm256<1024, 0><<<dim3(16, 16), 512, 0, stream>>>(
        x_bf, w1_bf, xz, 4096, nullptr, nullptr, nullptr);

    // 2. causal depthwise conv + bias + silu -> xs (bf16)
    conv_silu<<<(BB * LL * DIN) / 256, 256, 0, stream>>>(xz, conv_w, conv_b, xs_bf);

    // 3. dt/Bp/Cp fused GEMM  (M=4096, N=2304 padded, K=2048)
    gemm256<2048, 1><<<dim3(9, 16), 512, 0, stream>>>(
        xs_bf, wdtbc_bf, dtbuf, DIN, dt_b, Bp, Cp);

    // 4. chunked selective scan
    scan1<<<BB * NC * 8, 256, 0, stream>>>(dtbuf, xs_bf, Bp, A_log, aprod, hout);
    scan2<<<(BB * NST * DIN) / 256, 256, 0, stream>>>(aprod, hout, hin);
    scan3<<<BB * NC * 8, 256, 0, stream>>>(dtbuf, xs_bf, xz, Bp, Cp, hin,
                                           A_log, D_param, y_bf);

    // 5. out = y_gated @ out_proj_w^T   (M=4096, N=1024, K=2048)
    gemm256<2048, 0><<<dim3(4, 16), 512, 0, stream>>>(
        y_bf, wout_bf, out, DMODEL, nullptr, nullptr, nullptr);
}

// Round 12
// 437.340 us; speedup vs baseline: 5.2586x; 1.1235x over previous
//
#include <hip/hip_runtime.h>
#include <cmath>

#define BB 2
#define LL 2048
#define DMODEL 1024
#define DIN 2048
#define NST 16
#define NC 32      // scan chunks
#define TC 64      // timesteps per chunk

typedef short short8 __attribute__((ext_vector_type(8)));
typedef float f32x4 __attribute__((ext_vector_type(4)));
typedef unsigned short u16;

__device__ __forceinline__ float bf2f(u16 u) {
    union { unsigned u; float f; } v; v.u = ((unsigned)u) << 16; return v.f;
}
__device__ __forceinline__ u16 f2bf(float f) {
    union { float f; unsigned u; } v; v.f = f;
    unsigned r = v.u + 0x7FFFu + ((v.u >> 16) & 1u);
    return (u16)(r >> 16);
}

// ---------------------------------------------------------------------------
// f32 -> bf16 conversion, 4 elements/thread
// ---------------------------------------------------------------------------
__global__ __launch_bounds__(256) void cvt_bf16(const float* __restrict__ in,
                                                u16* __restrict__ out) {
    int i = (blockIdx.x * 256 + threadIdx.x) * 4;
    float4 v = *reinterpret_cast<const float4*>(in + i);
    ushort4 o = {f2bf(v.x), f2bf(v.y), f2bf(v.z), f2bf(v.w)};
    *reinterpret_cast<ushort4*>(out + i) = o;
}

// ---------------------------------------------------------------------------
// 2-phase double-buffered 128x128 bf16 MFMA GEMM. C[m,n]=sum_k A[m,k]*B[n,k].
// BK=64, 256 thr (4 waves 2x2, 64x64/wave), LDS 64 KiB -> 2 blocks/CU.
// Per K-tile: STAGE(t+1) issued FIRST, then ds_read(t)+MFMA(t), then the
// single drain+barrier (__syncthreads emits vmcnt(0) lgkmcnt(0) + s_barrier).
// T2 swizzle: pre-swizzled global source + XOR'd ds_read (verified r7, 0 conf).
// EPI 0: f32 C. EPI 1: dt/Bp/Cp routing + softplus. EPI 2: bf16 C.
// ---------------------------------------------------------------------------
template <int KDIM, int EPI>
__global__ __launch_bounds__(256, 2) void gemm128(const u16* __restrict__ A,
                                                  const u16* __restrict__ B,
                                                  void* __restrict__ Cout, int N,
                                                  const float* __restrict__ bias,
                                                  float* __restrict__ Bp,
                                                  float* __restrict__ Cp) {
    constexpr int NT = KDIM / 64;
    __shared__ u16 lds[32768];   // 64 KiB: A0,B0,A1,B1 of 128x64 u16 each
    const int tid = threadIdx.x;
    const int lane = tid & 63;
    const int wave = tid >> 6;
    const int bm = blockIdx.y * 128;
    const int bn = blockIdx.x * 128;
    const int wr = (wave >> 1) * 64;
    const int wc = (wave & 1) * 64;
    const int fr = lane & 15;
    const int kg8 = (lane >> 4) * 8;

    u16* const A0 = lds;
    u16* const B0 = lds + 8192;
    u16* const A1 = lds + 16384;
    u16* const B1 = lds + 24576;

    f32x4 acc[4][4];
#pragma unroll
    for (int i = 0; i < 4; ++i)
#pragma unroll
        for (int j = 0; j < 4; ++j) acc[i][j] = (f32x4){0.f, 0.f, 0.f, 0.f};

    // stage a 128x64 tile: 1024 x 16B chunks, 4 per thread; source pre-swizzled
    // (involution c ^= (c>>4)&7 in 16B-chunk units) so reads use the same XOR.
    auto STAGE = [&](const u16* __restrict__ G, int br, int kt, u16* dst) {
#pragma unroll
        for (int rr = 0; rr < 4; ++rr) {
            int c = rr * 256 + tid;
            int cs = c ^ ((c >> 4) & 7);
            __builtin_amdgcn_global_load_lds(
                (const __attribute__((address_space(1))) void*)(
                    G + (size_t)(br + (cs >> 3)) * KDIM + kt + ((cs & 7) << 3)),
                (__attribute__((address_space(3))) void*)(dst + c * 8), 16, 0, 0);
        }
    };
    auto LDSW = [&](const u16* tile, int row, int k) -> short8 {
        int u = row * 64 + k;
        u ^= ((u >> 7) & 7) << 3;
        return *reinterpret_cast<const short8*>(tile + u);
    };

    // prologue: tile 0
    STAGE(A, bm, 0, A0);
    STAGE(B, bn, 0, B0);
    __syncthreads();

#pragma unroll 1
    for (int t = 0; t < NT; ++t) {
        const u16* const Ac = (t & 1) ? A1 : A0;
        const u16* const Bc = (t & 1) ? B1 : B0;
        u16* const An = (t & 1) ? A0 : A1;
        u16* const Bn = (t & 1) ? B0 : B1;

        // issue next-tile loads BEFORE compute (hide HBM under MFMA)
        if (t + 1 < NT) {
            STAGE(A, bm, (t + 1) * 64, An);
            STAGE(B, bn, (t + 1) * 64, Bn);
        }

        short8 af[4][2], bf[4][2];
#pragma unroll
        for (int f = 0; f < 4; ++f)
#pragma unroll
            for (int ks = 0; ks < 2; ++ks)
                af[f][ks] = LDSW(Ac, wr + f * 16 + fr, ks * 32 + kg8);
#pragma unroll
        for (int j = 0; j < 4; ++j)
#pragma unroll
            for (int ks = 0; ks < 2; ++ks)
                bf[j][ks] = LDSW(Bc, wc + j * 16 + fr, ks * 32 + kg8);

#pragma unroll
        for (int ks = 0; ks < 2; ++ks)
#pragma unroll
            for (int f = 0; f < 4; ++f)
#pragma unroll
                for (int j = 0; j < 4; ++j)
                    acc[f][j] = __builtin_amdgcn_mfma_f32_16x16x32_bf16(
                        af[f][ks], bf[j][ks], acc[f][j], 0, 0, 0);

        // single per-tile drain: vmcnt(0)+lgkmcnt(0)+barrier (t+1 tile ready)
        __syncthreads();
    }

    // epilogue
    const int crow0 = (lane >> 4) * 4;
    const int ccol = lane & 15;
#pragma unroll
    for (int f = 0; f < 4; ++f)
#pragma unroll
        for (int j = 0; j < 4; ++j) {
            const int col = bn + wc + j * 16 + ccol;
            if (EPI == 1 && col >= DIN + 32) continue;
            float bv = (EPI == 1 && col < DIN) ? bias[col] : 0.f;
#pragma unroll
            for (int r = 0; r < 4; ++r) {
                const int row = bm + wr + f * 16 + crow0 + r;
                float v = acc[f][j][r];
                if (EPI == 0) {
                    ((float*)Cout)[(size_t)row * N + col] = v;
                } else if (EPI == 2) {
                    ((u16*)Cout)[(size_t)row * N + col] = f2bf(v);
                } else {
                    if (col < DIN) {
                        v += bv;
                        v = (v > 20.0f) ? v : log1pf(__expf(v));
                        ((float*)Cout)[(size_t)row * DIN + col] = v;
                    } else if (col < DIN + 16) {
                        Bp[(size_t)row * NST + (col - DIN)] = v;
                    } else {
                        Cp[(size_t)row * NST + (col - DIN - 16)] = v;
                    }
                }
            }
        }
}

// ---------------------------------------------------------------------------
// Depthwise causal conv (K=4) + bias + SiLU; reads bf16 xz, writes bf16 xs
// ---------------------------------------------------------------------------
__global__ __launch_bounds__(256) void conv_silu(const u16* __restrict__ xz,
                                                 const float* __restrict__ w,
                                                 const float* __restrict__ b,
                                                 u16* __restrict__ xsb) {
    int idx = blockIdx.x * 256 + threadIdx.x;   // B*L*DIN
    int d = idx & (DIN - 1);
    int t = (idx >> 11) & (LL - 1);
    int bb = idx >> 22;
    const u16* xp = xz + (size_t)bb * LL * 4096;
    float acc = b[d];
#pragma unroll
    for (int k = 0; k < 4; ++k) {
        int tt = t - 3 + k;
        if (tt >= 0) acc = fmaf(w[d * 4 + k], bf2f(xp[(size_t)tt * 4096 + d]), acc);
    }
    float s = acc / (1.0f + __expf(-acc));
    xsb[idx] = f2bf(s);
}

// ---------------------------------------------------------------------------
// Scan pass 1: per-chunk summaries (aprod = prod a, hout = local scan, h0=0)
// ---------------------------------------------------------------------------
__global__ __launch_bounds__(256) void scan1(const float* __restrict__ dt,
                                             const u16* __restrict__ xs,
                                             const float* __restrict__ Bp,
                                             const float* __restrict__ A_log,
                                             float* __restrict__ aprod,
                                             float* __restrict__ hout) {
    const int db = blockIdx.x & 7;
    const int c = (blockIdx.x >> 3) & (NC - 1);
    const int b = blockIdx.x >> 8;
    const int d = db * 256 + threadIdx.x;
    const int t0 = c * TC;

    __shared__ float Bs[TC * NST];
    for (int i = threadIdx.x; i < TC * NST; i += 256)
        Bs[i] = Bp[((size_t)b * LL + t0) * NST + i];
    __syncthreads();

    float Ac[NST];
#pragma unroll
    for (int n = 0; n < NST; ++n) Ac[n] = -__expf(A_log[d * NST + n]);

    float ap[NST], h[NST];
#pragma unroll
    for (int n = 0; n < NST; ++n) { ap[n] = 1.0f; h[n] = 0.0f; }

    const float* dtp = dt + ((size_t)b * LL + t0) * DIN + d;
    const u16*  xp  = xs + ((size_t)b * LL + t0) * DIN + d;

    for (int tt = 0; tt < TC; ++tt) {
        float dtv = dtp[(size_t)tt * DIN];
        float xv = bf2f(xp[(size_t)tt * DIN]);
        float bx = dtv * xv;
#pragma unroll
        for (int n = 0; n < NST; ++n) {
            float a = __expf(dtv * Ac[n]);
            ap[n] *= a;
            h[n] = fmaf(a, h[n], bx * Bs[tt * NST + n]);
        }
    }
#pragma unroll
    for (int n = 0; n < NST; ++n) {
        size_t idx = (((size_t)(b * NC + c) * NST) + n) * DIN + d;
        aprod[idx] = ap[n];
        hout[idx] = h[n];
    }
}

// ---------------------------------------------------------------------------
// Scan pass 2: cross-chunk combine. Thread per (b,n,d); 32 sequential chunks.
// ---------------------------------------------------------------------------
__global__ __launch_bounds__(256) void scan2(const float* __restrict__ aprod,
                                             const float* __restrict__ hout,
                                             float* __restrict__ hin) {
    const int gid = blockIdx.x * 256 + threadIdx.x;  // B*NST*DIN
    const int d = gid & (DIN - 1);
    const int n = (gid >> 11) & (NST - 1);
    const int b = gid >> 15;
    float h = 0.0f;
    for (int c = 0; c < NC; ++c) {
        size_t idx = (((size_t)(b * NC + c) * NST) + n) * DIN + d;
        hin[idx] = h;
        h = fmaf(aprod[idx], h, hout[idx]);
    }
}

// ---------------------------------------------------------------------------
// Scan pass 3: full scan within chunk from hin; fuse +D*xs, *silu(z), bf16 out
// ---------------------------------------------------------------------------
__global__ __launch_bounds__(256) void scan3(const float* __restrict__ dt,
                                             const u16* __restrict__ xs,
                                             const u16* __restrict__ xz,
                                             const float* __restrict__ Bp,
                                             const float* __restrict__ Cp,
                                             const float* __restrict__ hin,
                                             const float* __restrict__ A_log,
                                             const float* __restrict__ Dp,
                                             u16* __restrict__ ybf) {
    const int db = blockIdx.x & 7;
    const int c = (blockIdx.x >> 3) & (NC - 1);
    const int b = blockIdx.x >> 8;
    const int d = db * 256 + threadIdx.x;
    const int t0 = c * TC;

    __shared__ float Bs[TC * NST];
    __shared__ float Cs[TC * NST];
    for (int i = threadIdx.x; i < TC * NST; i += 256) {
        Bs[i] = Bp[((size_t)b * LL + t0) * NST + i];
        Cs[i] = Cp[((size_t)b * LL + t0) * NST + i];
    }
    __syncthreads();

    float Ac[NST], h[NST];
#pragma unroll
    for (int n = 0; n < NST; ++n) {
        Ac[n] = -__expf(A_log[d * NST + n]);
        h[n] = hin[(((size_t)(b * NC + c) * NST) + n) * DIN + d];
    }
    const float Dv = Dp[d];

    const float* dtp = dt + ((size_t)b * LL + t0) * DIN + d;
    const u16*  xp  = xs + ((size_t)b * LL + t0) * DIN + d;
    const u16*  zp  = xz + ((size_t)b * LL + t0) * 4096 + DIN + d;
    u16* yp = ybf + ((size_t)b * LL + t0) * DIN + d;

    for (int tt = 0; tt < TC; ++tt) {
        float dtv = dtp[(size_t)tt * DIN];
        float xv = bf2f(xp[(size_t)tt * DIN]);
        float zv = bf2f(zp[(size_t)tt * 4096]);
        float bx = dtv * xv;
        float y = 0.0f;
#pragma unroll
        for (int n = 0; n < NST; ++n) {
            float a = __expf(dtv * Ac[n]);
            h[n] = fmaf(a, h[n], bx * Bs[tt * NST + n]);
            y = fmaf(h[n], Cs[tt * NST + n], y);
        }
        y = fmaf(Dv, xv, y);
        float g = zv / (1.0f + __expf(-zv));
        yp[(size_t)tt * DIN] = f2bf(y * g);
    }
}

// ---------------------------------------------------------------------------
extern "C" void kernel_launch(void* const* d_in, const int* in_sizes, int n_in,
                              void* d_out, int out_size, void* d_ws, size_t ws_size,
                              hipStream_t stream) {
    const float* x          = (const float*)d_in[0];
    const float* in_proj_w  = (const float*)d_in[1];
    const float* conv_w     = (const float*)d_in[2];
    const float* conv_b     = (const float*)d_in[3];
    const float* dt_w       = (const float*)d_in[4];
    const float* dt_b       = (const float*)d_in[5];
    const float* B_proj_w   = (const float*)d_in[6];
    const float* C_proj_w   = (const float*)d_in[7];
    const float* A_log      = (const float*)d_in[8];
    const float* D_param    = (const float*)d_in[9];
    const float* out_proj_w = (const float*)d_in[10];
    float* out = (float*)d_out;
    float* ws  = (float*)d_ws;

    // f32 region (float offsets)
    float* dtbuf = ws;               //  8,388,608
    float* Bp    = ws + 8388608;     //     65,536
    float* Cp    = ws + 8454144;     //     65,536
    float* aprod = ws + 8519680;     //  2,097,152
    float* hout  = ws + 10616832;    //  2,097,152
    float* hin   = ws + 12713984;    //  2,097,152  (end 14,811,136)
    // bf16 region
    u16* bfbase   = (u16*)(ws + 14811136);
    u16* x_bf     = bfbase;                 // 4,194,304 (dead after gemm1)
    u16* w1_bf    = bfbase + 4194304;       // 4,194,304 (dead after gemm1)
    u16* y_bf     = bfbase;                 // 8,388,608 (aliases x_bf+w1_bf)
    u16* xz_bf    = bfbase + 8388608;       // 16,777,216 (B,L,4096)
    u16* wdtbc_bf = bfbase + 25165824;      // 2176*2048 = 4,456,448
    u16* wout_bf  = bfbase + 29622272;      // 2,097,152
    u16* xs_bf    = bfbase + 31719424;      // 8,388,608

    const int M = BB * LL;  // 4096

    // 0. bf16 conversions: x, in_proj_w, [dt_w|B_proj|C_proj], out_proj_w
    cvt_bf16<<<4194304 / 1024, 256, 0, stream>>>(x, x_bf);
    cvt_bf16<<<4194304 / 1024, 256, 0, stream>>>(in_proj_w, w1_bf);
    cvt_bf16<<<4194304 / 1024, 256, 0, stream>>>(dt_w, wdtbc_bf);
    cvt_bf16<<<32768 / 1024, 256, 0, stream>>>(B_proj_w, wdtbc_bf + (size_t)DIN * DIN);
    cvt_bf16<<<32768 / 1024, 256, 0, stream>>>(C_proj_w, wdtbc_bf + (size_t)(DIN + 16) * DIN);
    cvt_bf16<<<2097152 / 1024, 256, 0, stream>>>(out_proj_w, wout_bf);

    // 1. xz = x @ in_proj_w^T   (M=4096, N=4096, K=1024), bf16 out
    gemm128<1024, 2><<<dim3(32, 32), 256, 0, stream>>>(
        x_bf, w1_bf, xz_bf, 4096, nullptr, nullptr, nullptr);

    // 2. causal depthwise conv + bias + silu -> xs (bf16)
    conv_silu<<<(BB * LL * DIN) / 256, 256, 0, stream>>>(xz_bf, conv_w, conv_b, xs_bf);

    // 3. dt/Bp/Cp fused GEMM  (M=4096, N=2176, K=2048)
    gemm128<2048, 1><<<dim3(17, 32), 256, 0, stream>>>(
        xs_bf, wdtbc_bf, dtbuf, DIN, dt_b, Bp, Cp);

    // 4. chunked selective scan
    scan1<<<BB * NC * 8, 256, 0, stream>>>(dtbuf, xs_bf, Bp, A_log, aprod, hout);
    scan2<<<(BB * NST * DIN) / 256, 256, 0, stream>>>(aprod, hout, hin);
    scan3<<<BB * NC * 8, 256, 0, stream>>>(dtbuf, xs_bf, xz_bf, Bp, Cp, hin,
                                           A_log, D_param, y_bf);

    // 5. out = y_gated @ out_proj_w^T   (M=4096, N=1024, K=2048)
    gemm128<2048, 0><<<dim3(8, 32), 256, 0, stream>>>(
        y_bf, wout_bf, out, DMODEL, nullptr, nullptr, nullptr);
}

// Round 13
// 413.283 us; speedup vs baseline: 5.5647x; 1.0582x over previous
//
#include <hip/hip_runtime.h>
#include <cmath>

#define BB 2
#define LL 2048
#define DMODEL 1024
#define DIN 2048
#define NST 16
#define NC 32      // scan chunks
#define TC 64      // timesteps per chunk

typedef short short8 __attribute__((ext_vector_type(8)));
typedef float f32x4 __attribute__((ext_vector_type(4)));
typedef unsigned short u16;

__device__ __forceinline__ float bf2f(u16 u) {
    union { unsigned u; float f; } v; v.u = ((unsigned)u) << 16; return v.f;
}
__device__ __forceinline__ u16 f2bf(float f) {
    union { float f; unsigned u; } v; v.f = f;
    unsigned r = v.u + 0x7FFFu + ((v.u >> 16) & 1u);
    return (u16)(r >> 16);
}

// ---------------------------------------------------------------------------
// Fused f32 -> bf16 conversion for all 6 inputs (one launch).
// Each block converts 1024 contiguous elements (256 thr x 4).
// ---------------------------------------------------------------------------
__global__ __launch_bounds__(256) void cvt_all(const float* __restrict__ x,
                                               const float* __restrict__ w1,
                                               const float* __restrict__ dtw,
                                               const float* __restrict__ Bw,
                                               const float* __restrict__ Cw,
                                               const float* __restrict__ wo,
                                               u16* __restrict__ x_bf,
                                               u16* __restrict__ w1_bf,
                                               u16* __restrict__ wdtbc_bf,
                                               u16* __restrict__ wout_bf) {
    int blk = blockIdx.x;
    const float* src; u16* dst; int off;
    if (blk < 4096)        { src = x;   dst = x_bf;   off = blk; }
    else if (blk < 8192)   { src = w1;  dst = w1_bf;  off = blk - 4096; }
    else if (blk < 12288)  { src = dtw; dst = wdtbc_bf; off = blk - 8192; }
    else if (blk < 12320)  { src = Bw;  dst = wdtbc_bf + (size_t)DIN * DIN; off = blk - 12288; }
    else if (blk < 12352)  { src = Cw;  dst = wdtbc_bf + (size_t)(DIN + 16) * DIN; off = blk - 12320; }
    else                   { src = wo;  dst = wout_bf; off = blk - 12352; }
    int i = off * 1024 + threadIdx.x * 4;
    float4 v = *reinterpret_cast<const float4*>(src + i);
    ushort4 o = {f2bf(v.x), f2bf(v.y), f2bf(v.z), f2bf(v.w)};
    *reinterpret_cast<ushort4*>(dst + i) = o;
}

// ---------------------------------------------------------------------------
// 2-phase double-buffered 128x128 bf16 MFMA GEMM, BK=32 (m97 geometry).
// 256 thr (4 waves 2x2, 64x64/wave). LDS 32 KiB -> 4 blocks/CU
// (__launch_bounds__(256,4) caps VGPR at 128). Per K-tile: STAGE(t+1) first
// (4 x global_load_lds), then 8 x ds_read_b128 + 16 MFMA, then one
// __syncthreads drain. At BK=32 a wave's ds_read covers a contiguous 1 KiB
// block (16 rows x 64 B) -> naturally bank-conflict-free, no swizzle needed.
// EPI 0: f32 C. EPI 1: dt/Bp/Cp routing + softplus. EPI 2: bf16 C.
// ---------------------------------------------------------------------------
template <int KDIM, int EPI>
__global__ __launch_bounds__(256, 4) void gemm128(const u16* __restrict__ A,
                                                  const u16* __restrict__ B,
                                                  void* __restrict__ Cout, int N,
                                                  const float* __restrict__ bias,
                                                  float* __restrict__ Bp,
                                                  float* __restrict__ Cp) {
    constexpr int NT = KDIM / 32;
    __shared__ u16 lds[16384];   // 32 KiB: A0,B0,A1,B1 of 128x32 u16 (8 KB each)
    const int tid = threadIdx.x;
    const int lane = tid & 63;
    const int wave = tid >> 6;
    const int bm = blockIdx.y * 128;
    const int bn = blockIdx.x * 128;
    const int wr = (wave >> 1) * 64;
    const int wc = (wave & 1) * 64;
    const int fr = lane & 15;
    const int kg8 = (lane >> 4) * 8;

    u16* const A0 = lds;
    u16* const B0 = lds + 4096;
    u16* const A1 = lds + 8192;
    u16* const B1 = lds + 12288;

    f32x4 acc[4][4];
#pragma unroll
    for (int i = 0; i < 4; ++i)
#pragma unroll
        for (int j = 0; j < 4; ++j) acc[i][j] = (f32x4){0.f, 0.f, 0.f, 0.f};

    // stage a 128x32 tile: 512 x 16B chunks, 2 per thread, linear layout.
    // chunk c: row = c>>2, k-col = (c&3)*8 u16. LDS dest = base + lane*16B.
    auto STAGE = [&](const u16* __restrict__ G, int br, int kt, u16* dst) {
#pragma unroll
        for (int rr = 0; rr < 2; ++rr) {
            int c = rr * 256 + tid;
            __builtin_amdgcn_global_load_lds(
                (const __attribute__((address_space(1))) void*)(
                    G + (size_t)(br + (c >> 2)) * KDIM + kt + ((c & 3) << 3)),
                (__attribute__((address_space(3))) void*)(dst + c * 8), 16, 0, 0);
        }
    };

    // prologue: tile 0
    STAGE(A, bm, 0, A0);
    STAGE(B, bn, 0, B0);
    __syncthreads();

#pragma unroll 1
    for (int t = 0; t < NT; ++t) {
        const u16* const Ac = (t & 1) ? A1 : A0;
        const u16* const Bc = (t & 1) ? B1 : B0;
        u16* const An = (t & 1) ? A0 : A1;
        u16* const Bn = (t & 1) ? B0 : B1;

        // issue next-tile loads BEFORE compute (hide HBM under MFMA)
        if (t + 1 < NT) {
            STAGE(A, bm, (t + 1) * 32, An);
            STAGE(B, bn, (t + 1) * 32, Bn);
        }

        short8 af[4], bf[4];
#pragma unroll
        for (int f = 0; f < 4; ++f)
            af[f] = *reinterpret_cast<const short8*>(Ac + (wr + f * 16 + fr) * 32 + kg8);
#pragma unroll
        for (int j = 0; j < 4; ++j)
            bf[j] = *reinterpret_cast<const short8*>(Bc + (wc + j * 16 + fr) * 32 + kg8);

#pragma unroll
        for (int f = 0; f < 4; ++f)
#pragma unroll
            for (int j = 0; j < 4; ++j)
                acc[f][j] = __builtin_amdgcn_mfma_f32_16x16x32_bf16(
                    af[f], bf[j], acc[f][j], 0, 0, 0);

        // single per-tile drain: vmcnt(0)+lgkmcnt(0)+barrier (t+1 tile ready)
        __syncthreads();
    }

    // epilogue
    const int crow0 = (lane >> 4) * 4;
    const int ccol = lane & 15;
#pragma unroll
    for (int f = 0; f < 4; ++f)
#pragma unroll
        for (int j = 0; j < 4; ++j) {
            const int col = bn + wc + j * 16 + ccol;
            if (EPI == 1 && col >= DIN + 32) continue;
            float bv = (EPI == 1 && col < DIN) ? bias[col] : 0.f;
#pragma unroll
            for (int r = 0; r < 4; ++r) {
                const int row = bm + wr + f * 16 + crow0 + r;
                float v = acc[f][j][r];
                if (EPI == 0) {
                    ((float*)Cout)[(size_t)row * N + col] = v;
                } else if (EPI == 2) {
                    ((u16*)Cout)[(size_t)row * N + col] = f2bf(v);
                } else {
                    if (col < DIN) {
                        v += bv;
                        v = (v > 20.0f) ? v : log1pf(__expf(v));
                        ((float*)Cout)[(size_t)row * DIN + col] = v;
                    } else if (col < DIN + 16) {
                        Bp[(size_t)row * NST + (col - DIN)] = v;
                    } else {
                        Cp[(size_t)row * NST + (col - DIN - 16)] = v;
                    }
                }
            }
        }
}

// ---------------------------------------------------------------------------
// Depthwise causal conv (K=4) + bias + SiLU; reads bf16 xz, writes bf16 xs
// ---------------------------------------------------------------------------
__global__ __launch_bounds__(256) void conv_silu(const u16* __restrict__ xz,
                                                 const float* __restrict__ w,
                                                 const float* __restrict__ b,
                                                 u16* __restrict__ xsb) {
    int idx = blockIdx.x * 256 + threadIdx.x;   // B*L*DIN
    int d = idx & (DIN - 1);
    int t = (idx >> 11) & (LL - 1);
    int bb = idx >> 22;
    const u16* xp = xz + (size_t)bb * LL * 4096;
    float acc = b[d];
#pragma unroll
    for (int k = 0; k < 4; ++k) {
        int tt = t - 3 + k;
        if (tt >= 0) acc = fmaf(w[d * 4 + k], bf2f(xp[(size_t)tt * 4096 + d]), acc);
    }
    float s = acc / (1.0f + __expf(-acc));
    xsb[idx] = f2bf(s);
}

// ---------------------------------------------------------------------------
// Scan pass 1: per-chunk summaries (aprod = prod a, hout = local scan, h0=0)
// ---------------------------------------------------------------------------
__global__ __launch_bounds__(256) void scan1(const float* __restrict__ dt,
                                             const u16* __restrict__ xs,
                                             const float* __restrict__ Bp,
                                             const float* __restrict__ A_log,
                                             float* __restrict__ aprod,
                                             float* __restrict__ hout) {
    const int db = blockIdx.x & 7;
    const int c = (blockIdx.x >> 3) & (NC - 1);
    const int b = blockIdx.x >> 8;
    const int d = db * 256 + threadIdx.x;
    const int t0 = c * TC;

    __shared__ float Bs[TC * NST];
    for (int i = threadIdx.x; i < TC * NST; i += 256)
        Bs[i] = Bp[((size_t)b * LL + t0) * NST + i];
    __syncthreads();

    float Ac[NST];
#pragma unroll
    for (int n = 0; n < NST; ++n) Ac[n] = -__expf(A_log[d * NST + n]);

    float ap[NST], h[NST];
#pragma unroll
    for (int n = 0; n < NST; ++n) { ap[n] = 1.0f; h[n] = 0.0f; }

    const float* dtp = dt + ((size_t)b * LL + t0) * DIN + d;
    const u16*  xp  = xs + ((size_t)b * LL + t0) * DIN + d;

    for (int tt = 0; tt < TC; ++tt) {
        float dtv = dtp[(size_t)tt * DIN];
        float xv = bf2f(xp[(size_t)tt * DIN]);
        float bx = dtv * xv;
#pragma unroll
        for (int n = 0; n < NST; ++n) {
            float a = __expf(dtv * Ac[n]);
            ap[n] *= a;
            h[n] = fmaf(a, h[n], bx * Bs[tt * NST + n]);
        }
    }
#pragma unroll
    for (int n = 0; n < NST; ++n) {
        size_t idx = (((size_t)(b * NC + c) * NST) + n) * DIN + d;
        aprod[idx] = ap[n];
        hout[idx] = h[n];
    }
}

// ---------------------------------------------------------------------------
// Scan pass 2: cross-chunk combine. Thread per (b,n,d); 32 sequential chunks.
// ---------------------------------------------------------------------------
__global__ __launch_bounds__(256) void scan2(const float* __restrict__ aprod,
                                             const float* __restrict__ hout,
                                             float* __restrict__ hin) {
    const int gid = blockIdx.x * 256 + threadIdx.x;  // B*NST*DIN
    const int d = gid & (DIN - 1);
    const int n = (gid >> 11) & (NST - 1);
    const int b = gid >> 15;
    float h = 0.0f;
    for (int c = 0; c < NC; ++c) {
        size_t idx = (((size_t)(b * NC + c) * NST) + n) * DIN + d;
        hin[idx] = h;
        h = fmaf(aprod[idx], h, hout[idx]);
    }
}

// ---------------------------------------------------------------------------
// Scan pass 3: full scan within chunk from hin; fuse +D*xs, *silu(z), bf16 out
// ---------------------------------------------------------------------------
__global__ __launch_bounds__(256) void scan3(const float* __restrict__ dt,
                                             const u16* __restrict__ xs,
                                             const u16* __restrict__ xz,
                                             const float* __restrict__ Bp,
                                             const float* __restrict__ Cp,
                                             const float* __restrict__ hin,
                                             const float* __restrict__ A_log,
                                             const float* __restrict__ Dp,
                                             u16* __restrict__ ybf) {
    const int db = blockIdx.x & 7;
    const int c = (blockIdx.x >> 3) & (NC - 1);
    const int b = blockIdx.x >> 8;
    const int d = db * 256 + threadIdx.x;
    const int t0 = c * TC;

    __shared__ float Bs[TC * NST];
    __shared__ float Cs[TC * NST];
    for (int i = threadIdx.x; i < TC * NST; i += 256) {
        Bs[i] = Bp[((size_t)b * LL + t0) * NST + i];
        Cs[i] = Cp[((size_t)b * LL + t0) * NST + i];
    }
    __syncthreads();

    float Ac[NST], h[NST];
#pragma unroll
    for (int n = 0; n < NST; ++n) {
        Ac[n] = -__expf(A_log[d * NST + n]);
        h[n] = hin[(((size_t)(b * NC + c) * NST) + n) * DIN + d];
    }
    const float Dv = Dp[d];

    const float* dtp = dt + ((size_t)b * LL + t0) * DIN + d;
    const u16*  xp  = xs + ((size_t)b * LL + t0) * DIN + d;
    const u16*  zp  = xz + ((size_t)b * LL + t0) * 4096 + DIN + d;
    u16* yp = ybf + ((size_t)b * LL + t0) * DIN + d;

    for (int tt = 0; tt < TC; ++tt) {
        float dtv = dtp[(size_t)tt * DIN];
        float xv = bf2f(xp[(size_t)tt * DIN]);
        float zv = bf2f(zp[(size_t)tt * 4096]);
        float bx = dtv * xv;
        float y = 0.0f;
#pragma unroll
        for (int n = 0; n < NST; ++n) {
            float a = __expf(dtv * Ac[n]);
            h[n] = fmaf(a, h[n], bx * Bs[tt * NST + n]);
            y = fmaf(h[n], Cs[tt * NST + n], y);
        }
        y = fmaf(Dv, xv, y);
        float g = zv / (1.0f + __expf(-zv));
        yp[(size_t)tt * DIN] = f2bf(y * g);
    }
}

// ---------------------------------------------------------------------------
extern "C" void kernel_launch(void* const* d_in, const int* in_sizes, int n_in,
                              void* d_out, int out_size, void* d_ws, size_t ws_size,
                              hipStream_t stream) {
    const float* x          = (const float*)d_in[0];
    const float* in_proj_w  = (const float*)d_in[1];
    const float* conv_w     = (const float*)d_in[2];
    const float* conv_b     = (const float*)d_in[3];
    const float* dt_w       = (const float*)d_in[4];
    const float* dt_b       = (const float*)d_in[5];
    const float* B_proj_w   = (const float*)d_in[6];
    const float* C_proj_w   = (const float*)d_in[7];
    const float* A_log      = (const float*)d_in[8];
    const float* D_param    = (const float*)d_in[9];
    const float* out_proj_w = (const float*)d_in[10];
    float* out = (float*)d_out;
    float* ws  = (float*)d_ws;

    // f32 region (float offsets)
    float* dtbuf = ws;               //  8,388,608
    float* Bp    = ws + 8388608;     //     65,536
    float* Cp    = ws + 8454144;     //     65,536
    float* aprod = ws + 8519680;     //  2,097,152
    float* hout  = ws + 10616832;    //  2,097,152
    float* hin   = ws + 12713984;    //  2,097,152  (end 14,811,136)
    // bf16 region
    u16* bfbase   = (u16*)(ws + 14811136);
    u16* x_bf     = bfbase;                 // 4,194,304 (dead after gemm1)
    u16* w1_bf    = bfbase + 4194304;       // 4,194,304 (dead after gemm1)
    u16* y_bf     = bfbase;                 // 8,388,608 (aliases x_bf+w1_bf)
    u16* xz_bf    = bfbase + 8388608;       // 16,777,216 (B,L,4096)
    u16* wdtbc_bf = bfbase + 25165824;      // 2176*2048 = 4,456,448
    u16* wout_bf  = bfbase + 29622272;      // 2,097,152
    u16* xs_bf    = bfbase + 31719424;      // 8,388,608

    const int M = BB * LL;  // 4096

    // 0. fused bf16 conversions (x, in_proj_w, [dt_w|B_proj|C_proj], out_proj_w)
    cvt_all<<<14400, 256, 0, stream>>>(x, in_proj_w, dt_w, B_proj_w, C_proj_w,
                                       out_proj_w, x_bf, w1_bf, wdtbc_bf, wout_bf);

    // 1. xz = x @ in_proj_w^T   (M=4096, N=4096, K=1024), bf16 out
    gemm128<1024, 2><<<dim3(32, 32), 256, 0, stream>>>(
        x_bf, w1_bf, xz_bf, 4096, nullptr, nullptr, nullptr);

    // 2. causal depthwise conv + bias + silu -> xs (bf16)
    conv_silu<<<(BB * LL * DIN) / 256, 256, 0, stream>>>(xz_bf, conv_w, conv_b, xs_bf);

    // 3. dt/Bp/Cp fused GEMM  (M=4096, N=2176, K=2048)
    gemm128<2048, 1><<<dim3(17, 32), 256, 0, stream>>>(
        xs_bf, wdtbc_bf, dtbuf, DIN, dt_b, Bp, Cp);

    // 4. chunked selective scan
    scan1<<<BB * NC * 8, 256, 0, stream>>>(dtbuf, xs_bf, Bp, A_log, aprod, hout);
    scan2<<<(BB * NST * DIN) / 256, 256, 0, stream>>>(aprod, hout, hin);
    scan3<<<BB * NC * 8, 256, 0, stream>>>(dtbuf, xs_bf, xz_bf, Bp, Cp, hin,
                                           A_log, D_param, y_bf);

    // 5. out = y_gated @ out_proj_w^T   (M=4096, N=1024, K=2048)
    gemm128<2048, 0><<<dim3(8, 32), 256, 0, stream>>>(
        y_bf, wout_bf, out, DMODEL, nullptr, nullptr, nullptr);
}

// Round 15
// 405.327 us; speedup vs baseline: 5.6739x; 1.0196x over previous
//
#include <hip/hip_runtime.h>
#include <cmath>

#define BB 2
#define LL 2048
#define DMODEL 1024
#define DIN 2048
#define NST 16
#define NC 32      // scan chunks
#define TC 64      // timesteps per chunk

typedef short short8 __attribute__((ext_vector_type(8)));
typedef float f32x4 __attribute__((ext_vector_type(4)));
typedef unsigned short u16;

__device__ __forceinline__ float bf2f(u16 u) {
    union { unsigned u; float f; } v; v.u = ((unsigned)u) << 16; return v.f;
}
__device__ __forceinline__ u16 f2bf(float f) {
    union { float f; unsigned u; } v; v.f = f;
    unsigned r = v.u + 0x7FFFu + ((v.u >> 16) & 1u);
    return (u16)(r >> 16);
}

// ---------------------------------------------------------------------------
// Fused f32 -> bf16 conversion for all 6 inputs (one launch).
// ---------------------------------------------------------------------------
__global__ __launch_bounds__(256) void cvt_all(const float* __restrict__ x,
                                               const float* __restrict__ w1,
                                               const float* __restrict__ dtw,
                                               const float* __restrict__ Bw,
                                               const float* __restrict__ Cw,
                                               const float* __restrict__ wo,
                                               u16* __restrict__ x_bf,
                                               u16* __restrict__ w1_bf,
                                               u16* __restrict__ wdtbc_bf,
                                               u16* __restrict__ wout_bf) {
    int blk = blockIdx.x;
    const float* src; u16* dst; int off;
    if (blk < 4096)        { src = x;   dst = x_bf;   off = blk; }
    else if (blk < 8192)   { src = w1;  dst = w1_bf;  off = blk - 4096; }
    else if (blk < 12288)  { src = dtw; dst = wdtbc_bf; off = blk - 8192; }
    else if (blk < 12320)  { src = Bw;  dst = wdtbc_bf + (size_t)DIN * DIN; off = blk - 12288; }
    else if (blk < 12352)  { src = Cw;  dst = wdtbc_bf + (size_t)(DIN + 16) * DIN; off = blk - 12320; }
    else                   { src = wo;  dst = wout_bf; off = blk - 12352; }
    int i = off * 1024 + threadIdx.x * 4;
    float4 v = *reinterpret_cast<const float4*>(src + i);
    ushort4 o = {f2bf(v.x), f2bf(v.y), f2bf(v.z), f2bf(v.w)};
    *reinterpret_cast<ushort4*>(dst + i) = o;
}

// ---------------------------------------------------------------------------
// 2-phase double-buffered 128x128 bf16 MFMA GEMM, BK=32.
// 256 thr (4 waves 2x2, 64x64/wave). LDS 32 KiB -> 4 blocks/CU.
// T1: bijective XCD re-group (m204) so each XCD owns contiguous tile ids
//     (4 A-rows x all cols) -> A-panels fetched once per XCD's L2.
// T2 (BK=32 form): kg' = kg ^ ((row>>1)&3) involution on 16B chunks, applied
//     to pre-swizzled global source + ds_read -> each 8-lane group spans 8
//     distinct bank quads (was 4-way conflict).
// EPI 0: f32 C. EPI 1: dt/Bp/Cp routing + softplus. EPI 2: bf16 C.
// ---------------------------------------------------------------------------
template <int KDIM, int EPI>
__global__ __launch_bounds__(256, 4) void gemm128(const u16* __restrict__ A,
                                                  const u16* __restrict__ B,
                                                  void* __restrict__ Cout, int N,
                                                  const float* __restrict__ bias,
                                                  float* __restrict__ Bp,
                                                  float* __restrict__ Cp) {
    constexpr int NT = KDIM / 32;
    __shared__ u16 lds[16384];   // 32 KiB: A0,B0,A1,B1 of 128x32 u16
    const int tid = threadIdx.x;
    const int lane = tid & 63;
    const int wave = tid >> 6;

    // T1: XCD-contiguous tile remap (bijective, m204)
    const int GX = gridDim.x;
    const int nwg = GX * gridDim.y;
    const int wgid = blockIdx.y * GX + blockIdx.x;   // HW-linear (x fastest)
    const int q = nwg >> 3, r = nwg & 7;
    const int xcd = wgid & 7, k = wgid >> 3;
    const int tile = (xcd < r ? xcd * (q + 1) : r * (q + 1) + (xcd - r) * q) + k;
    const int bm = (tile / GX) * 128;
    const int bn = (tile % GX) * 128;

    const int wr = (wave >> 1) * 64;
    const int wc = (wave & 1) * 64;
    const int fr = lane & 15;

    u16* const A0 = lds;
    u16* const B0 = lds + 4096;
    u16* const A1 = lds + 8192;
    u16* const B1 = lds + 12288;

    f32x4 acc[4][4];
#pragma unroll
    for (int i = 0; i < 4; ++i)
#pragma unroll
        for (int j = 0; j < 4; ++j) acc[i][j] = (f32x4){0.f, 0.f, 0.f, 0.f};

    // stage a 128x32 tile: 512 x 16B chunks, 2 per thread; source pre-swizzled
    // with the kg^((row>>1)&3) involution so LDS reads use the same XOR.
    auto STAGE = [&](const u16* __restrict__ G, int br, int kt, u16* dst) {
#pragma unroll
        for (int rr = 0; rr < 2; ++rr) {
            int c = rr * 256 + tid;                 // dst chunk (linear)
            int kgs = (c & 3) ^ ((c >> 3) & 3);     // swizzled k-group of source
            __builtin_amdgcn_global_load_lds(
                (const __attribute__((address_space(1))) void*)(
                    G + (size_t)(br + (c >> 2)) * KDIM + kt + (kgs << 3)),
                (__attribute__((address_space(3))) void*)(dst + c * 8), 16, 0, 0);
        }
    };
    auto LDSW = [&](const u16* tile_, int row) -> short8 {
        int kgx = ((lane >> 4) ^ ((row >> 1) & 3)) << 3;
        return *reinterpret_cast<const short8*>(tile_ + row * 32 + kgx);
    };

    // prologue: tile 0
    STAGE(A, bm, 0, A0);
    STAGE(B, bn, 0, B0);
    __syncthreads();

#pragma unroll 1
    for (int t = 0; t < NT; ++t) {
        const u16* const Ac = (t & 1) ? A1 : A0;
        const u16* const Bc = (t & 1) ? B1 : B0;
        u16* const An = (t & 1) ? A0 : A1;
        u16* const Bn = (t & 1) ? B0 : B1;

        // issue next-tile loads BEFORE compute (hide HBM/L2 under MFMA)
        if (t + 1 < NT) {
            STAGE(A, bm, (t + 1) * 32, An);
            STAGE(B, bn, (t + 1) * 32, Bn);
        }

        short8 af[4], bf[4];
#pragma unroll
        for (int f = 0; f < 4; ++f)
            af[f] = LDSW(Ac, wr + f * 16 + fr);
#pragma unroll
        for (int j = 0; j < 4; ++j)
            bf[j] = LDSW(Bc, wc + j * 16 + fr);

#pragma unroll
        for (int f = 0; f < 4; ++f)
#pragma unroll
            for (int j = 0; j < 4; ++j)
                acc[f][j] = __builtin_amdgcn_mfma_f32_16x16x32_bf16(
                    af[f], bf[j], acc[f][j], 0, 0, 0);

        // single per-tile drain: vmcnt(0)+lgkmcnt(0)+barrier
        __syncthreads();
    }

    // epilogue
    const int crow0 = (lane >> 4) * 4;
    const int ccol = lane & 15;
#pragma unroll
    for (int f = 0; f < 4; ++f)
#pragma unroll
        for (int j = 0; j < 4; ++j) {
            const int col = bn + wc + j * 16 + ccol;
            if (EPI == 1 && col >= DIN + 32) continue;
            float bv = (EPI == 1 && col < DIN) ? bias[col] : 0.f;
#pragma unroll
            for (int r2 = 0; r2 < 4; ++r2) {
                const int row = bm + wr + f * 16 + crow0 + r2;
                float v = acc[f][j][r2];
                if (EPI == 0) {
                    ((float*)Cout)[(size_t)row * N + col] = v;
                } else if (EPI == 2) {
                    ((u16*)Cout)[(size_t)row * N + col] = f2bf(v);
                } else {
                    if (col < DIN) {
                        v += bv;
                        v = (v > 20.0f) ? v : log1pf(__expf(v));
                        ((float*)Cout)[(size_t)row * DIN + col] = v;
                    } else if (col < DIN + 16) {
                        Bp[(size_t)row * NST + (col - DIN)] = v;
                    } else {
                        Cp[(size_t)row * NST + (col - DIN - 16)] = v;
                    }
                }
            }
        }
}

// ---------------------------------------------------------------------------
// Depthwise causal conv (K=4) + bias + SiLU; reads bf16 xz, writes bf16 xs
// ---------------------------------------------------------------------------
__global__ __launch_bounds__(256) void conv_silu(const u16* __restrict__ xz,
                                                 const float* __restrict__ w,
                                                 const float* __restrict__ b,
                                                 u16* __restrict__ xsb) {
    int idx = blockIdx.x * 256 + threadIdx.x;   // B*L*DIN
    int d = idx & (DIN - 1);
    int t = (idx >> 11) & (LL - 1);
    int bb = idx >> 22;
    const u16* xp = xz + (size_t)bb * LL * 4096;
    float acc = b[d];
#pragma unroll
    for (int k = 0; k < 4; ++k) {
        int tt = t - 3 + k;
        if (tt >= 0) acc = fmaf(w[d * 4 + k], bf2f(xp[(size_t)tt * 4096 + d]), acc);
    }
    float s = acc / (1.0f + __expf(-acc));
    xsb[idx] = f2bf(s);
}

// ---------------------------------------------------------------------------
// Scan pass 1: per-chunk summaries (aprod = prod a, hout = local scan, h0=0)
// ---------------------------------------------------------------------------
__global__ __launch_bounds__(256) void scan1(const float* __restrict__ dt,
                                             const u16* __restrict__ xs,
                                             const float* __restrict__ Bp,
                                             const float* __restrict__ A_log,
                                             float* __restrict__ aprod,
                                             float* __restrict__ hout) {
    const int db = blockIdx.x & 7;
    const int c = (blockIdx.x >> 3) & (NC - 1);
    const int b = blockIdx.x >> 8;
    const int d = db * 256 + threadIdx.x;
    const int t0 = c * TC;

    __shared__ float Bs[TC * NST];
    for (int i = threadIdx.x; i < TC * NST; i += 256)
        Bs[i] = Bp[((size_t)b * LL + t0) * NST + i];
    __syncthreads();

    float Ac[NST];
#pragma unroll
    for (int n = 0; n < NST; ++n) Ac[n] = -__expf(A_log[d * NST + n]);

    float ap[NST], h[NST];
#pragma unroll
    for (int n = 0; n < NST; ++n) { ap[n] = 1.0f; h[n] = 0.0f; }

    const float* dtp = dt + ((size_t)b * LL + t0) * DIN + d;
    const u16*  xp  = xs + ((size_t)b * LL + t0) * DIN + d;

    for (int tt = 0; tt < TC; ++tt) {
        float dtv = dtp[(size_t)tt * DIN];
        float xv = bf2f(xp[(size_t)tt * DIN]);
        float bx = dtv * xv;
#pragma unroll
        for (int n = 0; n < NST; ++n) {
            float a = __expf(dtv * Ac[n]);
            ap[n] *= a;
            h[n] = fmaf(a, h[n], bx * Bs[tt * NST + n]);
        }
    }
#pragma unroll
    for (int n = 0; n < NST; ++n) {
        size_t idx = (((size_t)(b * NC + c) * NST) + n) * DIN + d;
        aprod[idx] = ap[n];
        hout[idx] = h[n];
    }
}

// ---------------------------------------------------------------------------
// Scan pass 2: cross-chunk combine. Thread per (b,n,d); 32 sequential chunks.
// ---------------------------------------------------------------------------
__global__ __launch_bounds__(256) void scan2(const float* __restrict__ aprod,
                                             const float* __restrict__ hout,
                                             float* __restrict__ hin) {
    const int gid = blockIdx.x * 256 + threadIdx.x;  // B*NST*DIN
    const int d = gid & (DIN - 1);
    const int n = (gid >> 11) & (NST - 1);
    const int b = gid >> 15;
    float h = 0.0f;
    for (int c = 0; c < NC; ++c) {
        size_t idx = (((size_t)(b * NC + c) * NST) + n) * DIN + d;
        hin[idx] = h;
        h = fmaf(aprod[idx], h, hout[idx]);
    }
}

// ---------------------------------------------------------------------------
// Scan pass 3: full scan within chunk from hin; fuse +D*xs, *silu(z), bf16 out
// ---------------------------------------------------------------------------
__global__ __launch_bounds__(256) void scan3(const float* __restrict__ dt,
                                             const u16* __restrict__ xs,
                                             const u16* __restrict__ xz,
                                             const float* __restrict__ Bp,
                                             const float* __restrict__ Cp,
                                             const float* __restrict__ hin,
                                             const float* __restrict__ A_log,
                                             const float* __restrict__ Dp,
                                             u16* __restrict__ ybf) {
    const int db = blockIdx.x & 7;
    const int c = (blockIdx.x >> 3) & (NC - 1);
    const int b = blockIdx.x >> 8;
    const int d = db * 256 + threadIdx.x;
    const int t0 = c * TC;

    __shared__ float Bs[TC * NST];
    __shared__ float Cs[TC * NST];
    for (int i = threadIdx.x; i < TC * NST; i += 256) {
        Bs[i] = Bp[((size_t)b * LL + t0) * NST + i];
        Cs[i] = Cp[((size_t)b * LL + t0) * NST + i];
    }
    __syncthreads();

    float Ac[NST], h[NST];
#pragma unroll
    for (int n = 0; n < NST; ++n) {
        Ac[n] = -__expf(A_log[d * NST + n]);
        h[n] = hin[(((size_t)(b * NC + c) * NST) + n) * DIN + d];
    }
    const float Dv = Dp[d];

    const float* dtp = dt + ((size_t)b * LL + t0) * DIN + d;
    const u16*  xp  = xs + ((size_t)b * LL + t0) * DIN + d;
    const u16*  zp  = xz + ((size_t)b * LL + t0) * 4096 + DIN + d;
    u16* yp = ybf + ((size_t)b * LL + t0) * DIN + d;

    for (int tt = 0; tt < TC; ++tt) {
        float dtv = dtp[(size_t)tt * DIN];
        float xv = bf2f(xp[(size_t)tt * DIN]);
        float zv = bf2f(zp[(size_t)tt * 4096]);
        float bx = dtv * xv;
        float y = 0.0f;
#pragma unroll
        for (int n = 0; n < NST; ++n) {
            float a = __expf(dtv * Ac[n]);
            h[n] = fmaf(a, h[n], bx * Bs[tt * NST + n]);
            y = fmaf(h[n], Cs[tt * NST + n], y);
        }
        y = fmaf(Dv, xv, y);
        float g = zv / (1.0f + __expf(-zv));
        yp[(size_t)tt * DIN] = f2bf(y * g);
    }
}

// ---------------------------------------------------------------------------
extern "C" void kernel_launch(void* const* d_in, const int* in_sizes, int n_in,
                              void* d_out, int out_size, void* d_ws, size_t ws_size,
                              hipStream_t stream) {
    const float* x          = (const float*)d_in[0];
    const float* in_proj_w  = (const float*)d_in[1];
    const float* conv_w     = (const float*)d_in[2];
    const float* conv_b     = (const float*)d_in[3];
    const float* dt_w       = (const float*)d_in[4];
    const float* dt_b       = (const float*)d_in[5];
    const float* B_proj_w   = (const float*)d_in[6];
    const float* C_proj_w   = (const float*)d_in[7];
    const float* A_log      = (const float*)d_in[8];
    const float* D_param    = (const float*)d_in[9];
    const float* out_proj_w = (const float*)d_in[10];
    float* out = (float*)d_out;
    float* ws  = (float*)d_ws;

    // f32 region (float offsets)
    float* dtbuf = ws;               //  8,388,608
    float* Bp    = ws + 8388608;     //     65,536
    float* Cp    = ws + 8454144;     //     65,536
    float* aprod = ws + 8519680;     //  2,097,152
    float* hout  = ws + 10616832;    //  2,097,152
    float* hin   = ws + 12713984;    //  2,097,152  (end 14,811,136)
    // bf16 region
    u16* bfbase   = (u16*)(ws + 14811136);
    u16* x_bf     = bfbase;                 // 4,194,304 (dead after gemm1)
    u16* w1_bf    = bfbase + 4194304;       // 4,194,304 (dead after gemm1)
    u16* y_bf     = bfbase;                 // 8,388,608 (aliases x_bf+w1_bf)
    u16* xz_bf    = bfbase + 8388608;       // 16,777,216 (B,L,4096)
    u16* wdtbc_bf = bfbase + 25165824;      // 2176*2048 = 4,456,448
    u16* wout_bf  = bfbase + 29622272;      // 2,097,152
    u16* xs_bf    = bfbase + 31719424;      // 8,388,608

    const int M = BB * LL;  // 4096

    // 0. fused bf16 conversions
    cvt_all<<<14400, 256, 0, stream>>>(x, in_proj_w, dt_w, B_proj_w, C_proj_w,
                                       out_proj_w, x_bf, w1_bf, wdtbc_bf, wout_bf);

    // 1. xz = x @ in_proj_w^T   (M=4096, N=4096, K=1024), bf16 out
    gemm128<1024, 2><<<dim3(32, 32), 256, 0, stream>>>(
        x_bf, w1_bf, xz_bf, 4096, nullptr, nullptr, nullptr);

    // 2. causal depthwise conv + bias + silu -> xs (bf16)
    conv_silu<<<(BB * LL * DIN) / 256, 256, 0, stream>>>(xz_bf, conv_w, conv_b, xs_bf);

    // 3. dt/Bp/Cp fused GEMM  (M=4096, N=2176, K=2048)
    gemm128<2048, 1><<<dim3(17, 32), 256, 0, stream>>>(
        xs_bf, wdtbc_bf, dtbuf, DIN, dt_b, Bp, Cp);

    // 4. chunked selective scan
    scan1<<<BB * NC * 8, 256, 0, stream>>>(dtbuf, xs_bf, Bp, A_log, aprod, hout);
    scan2<<<(BB * NST * DIN) / 256, 256, 0, stream>>>(aprod, hout, hin);
    scan3<<<BB * NC * 8, 256, 0, stream>>>(dtbuf, xs_bf, xz_bf, Bp, Cp, hin,
                                           A_log, D_param, y_bf);

    // 5. out = y_gated @ out_proj_w^T   (M=4096, N=1024, K=2048)
    gemm128<2048, 0><<<dim3(8, 32), 256, 0, stream>>>(
        y_bf, wout_bf, out, DMODEL, nullptr, nullptr, nullptr);
}